// Round 1
// baseline (1018.069 us; speedup 1.0000x reference)
//
#include <hip/hip_runtime.h>
#include <stdint.h>

typedef unsigned short u16;
typedef __attribute__((ext_vector_type(8))) short short8;
typedef __attribute__((ext_vector_type(4))) float f32x4;

#define MFMA16(A,B,C) __builtin_amdgcn_mfma_f32_16x16x32_bf16(A,B,C,0,0,0)

static __device__ __forceinline__ u16 f2bf(float f) {
  union { float f; unsigned u; } v; v.f = f;
  unsigned r = v.u + 0x7FFFu + ((v.u >> 16) & 1u);
  return (u16)(r >> 16);
}

// global -> LDS direct copy, 16B per lane. LDS dest must be wave-uniform base
// (+ lane*16 implicit); global src is per-lane.
static __device__ __forceinline__ void gload16(const void* g, void* l) {
  __builtin_amdgcn_global_load_lds(
      (const __attribute__((address_space(1))) void*)(uintptr_t)g,
      (__attribute__((address_space(3))) void*)(uint32_t)(uintptr_t)l,
      16, 0, 0);
}

// ---------------- generic bf16 GEMM: C[M,N] = A[M,K] @ Wt[N,K]^T ------------
// 128x128 tile, BK=32, 4 waves each 64x64 (4x4 16x16x32 mfma tiles).
// Epilogue: +bias, +res1, +res2 (fp32), optional relu; out fp32 (Cf) or bf16 (Cb).
__global__ __launch_bounds__(256) void gemm_bt(
    const u16* __restrict__ A, const u16* __restrict__ Wt,
    float* __restrict__ Cf, u16* __restrict__ Cb,
    const float* __restrict__ bias,
    const float* __restrict__ res1, const float* __restrict__ res2,
    int M, int N, int K, int relu)
{
  __shared__ u16 lsA[128 * 32];
  __shared__ u16 lsB[128 * 32];
  const int tid = threadIdx.x;
  const int wid = tid >> 6, lane = tid & 63;
  const int col = lane & 15, kgr = lane >> 4;
  const int m0 = blockIdx.x * 128, n0 = blockIdx.y * 128;
  const int wm = (wid >> 1) * 64, wn = (wid & 1) * 64;
  f32x4 acc[4][4] = {};
  const int nk = K >> 5;
  for (int kt = 0; kt < nk; ++kt) {
    const int k0 = kt << 5;
#pragma unroll
    for (int i = 0; i < 2; ++i) {
      int e = i * 2048 + tid * 8;               // element index in 128x32 tile
      gload16(A  + (size_t)(m0 + (e >> 5)) * K + k0 + (e & 31), &lsA[i * 2048 + wid * 512]);
      gload16(Wt + (size_t)(n0 + (e >> 5)) * K + k0 + (e & 31), &lsB[i * 2048 + wid * 512]);
    }
    __syncthreads();
    short8 af[4], bfr[4];
#pragma unroll
    for (int t = 0; t < 4; ++t) {
      af[t]  = *(const short8*)&lsA[(wm + t * 16 + col) * 32 + kgr * 8];
      bfr[t] = *(const short8*)&lsB[(wn + t * 16 + col) * 32 + kgr * 8];
    }
#pragma unroll
    for (int mt = 0; mt < 4; ++mt)
#pragma unroll
      for (int nt = 0; nt < 4; ++nt)
        acc[mt][nt] = MFMA16(af[mt], bfr[nt], acc[mt][nt]);
    __syncthreads();
  }
#pragma unroll
  for (int nt = 0; nt < 4; ++nt) {
    const int n = n0 + wn + nt * 16 + col;
    const float bv = bias ? bias[n] : 0.f;
#pragma unroll
    for (int mt = 0; mt < 4; ++mt) {
#pragma unroll
      for (int r = 0; r < 4; ++r) {
        const int m = m0 + wm + mt * 16 + kgr * 4 + r;
        const size_t off = (size_t)m * N + n;
        float v = acc[mt][nt][r] + bv;
        if (res1) v += res1[off];
        if (res2) v += res2[off];
        if (relu) v = fmaxf(v, 0.f);
        if (Cf) Cf[off] = v; else Cb[off] = f2bf(v);
      }
    }
  }
}

// ---------------- LayerNorm (fp32 in, bf16 out), one row (D=1024) per block --
__global__ __launch_bounds__(256) void ln_rows(
    const float* __restrict__ x, const float* __restrict__ g,
    const float* __restrict__ bt, u16* __restrict__ out)
{
  const int row = blockIdx.x, tid = threadIdx.x;
  const float4 v = ((const float4*)(x + (size_t)row * 1024))[tid];
  float s  = v.x + v.y + v.z + v.w;
  float ss = v.x * v.x + v.y * v.y + v.z * v.z + v.w * v.w;
#pragma unroll
  for (int off = 32; off; off >>= 1) {
    s  += __shfl_xor(s, off);
    ss += __shfl_xor(ss, off);
  }
  __shared__ float red[8];
  const int wid = tid >> 6, lane = tid & 63;
  if (lane == 0) { red[wid] = s; red[4 + wid] = ss; }
  __syncthreads();
  s  = red[0] + red[1] + red[2] + red[3];
  ss = red[4] + red[5] + red[6] + red[7];
  const float mean = s * 0.0009765625f;
  const float var  = ss * 0.0009765625f - mean * mean;
  const float rstd = rsqrtf(var + 1e-5f);
  const float4 gg = ((const float4*)g)[tid];
  const float4 bb = ((const float4*)bt)[tid];
  uint2 ov;
  ov.x = (unsigned)f2bf((v.x - mean) * rstd * gg.x + bb.x) |
         ((unsigned)f2bf((v.y - mean) * rstd * gg.y + bb.y) << 16);
  ov.y = (unsigned)f2bf((v.z - mean) * rstd * gg.z + bb.z) |
         ((unsigned)f2bf((v.w - mean) * rstd * gg.w + bb.w) << 16);
  *(uint2*)(out + (size_t)row * 1024 + tid * 4) = ov;
}

// ---------------- weight packing --------------------------------------------
// [R][C] fp32 -> [C][R] bf16
__global__ __launch_bounds__(256) void transpose_w(
    const float* __restrict__ in, u16* __restrict__ out, int R, int C)
{
  __shared__ float t[32][33];
  const int c0 = blockIdx.x * 32, r0 = blockIdx.y * 32;
  const int tx = threadIdx.x & 31, ty = threadIdx.x >> 5;
#pragma unroll
  for (int i = 0; i < 32; i += 8)
    t[ty + i][tx] = in[(size_t)(r0 + ty + i) * C + c0 + tx];
  __syncthreads();
#pragma unroll
  for (int i = 0; i < 32; i += 8)
    out[(size_t)(c0 + ty + i) * R + r0 + tx] = f2bf(t[tx][ty + i]);
}

// w[H=16][D=1024][HS=64] fp32 -> out[(h*64+s)][c] bf16   (grid 2,32,16)
__global__ __launch_bounds__(256) void pack_head_w(
    const float* __restrict__ w, u16* __restrict__ out)
{
  __shared__ float t[32][33];
  const int h = blockIdx.z;
  const int s0 = blockIdx.x * 32, c0 = blockIdx.y * 32;
  const int tx = threadIdx.x & 31, ty = threadIdx.x >> 5;
#pragma unroll
  for (int i = 0; i < 32; i += 8)
    t[ty + i][tx] = w[((size_t)h * 1024 + c0 + ty + i) * 64 + s0 + tx];
  __syncthreads();
#pragma unroll
  for (int i = 0; i < 32; i += 8)
    out[((size_t)h * 64 + s0 + ty + i) * 1024 + c0 + tx] = f2bf(t[tx][ty + i]);
}

__global__ __launch_bounds__(256) void cvt_bf16(
    const float* __restrict__ in, u16* __restrict__ out)
{
  const int i = blockIdx.x * blockDim.x + threadIdx.x;
  const float4 v = ((const float4*)in)[i];
  uint2 ov;
  ov.x = (unsigned)f2bf(v.x) | ((unsigned)f2bf(v.y) << 16);
  ov.y = (unsigned)f2bf(v.z) | ((unsigned)f2bf(v.w) << 16);
  *(uint2*)(out + (size_t)i * 4) = ov;
}

// V slices [B,T,(coloff+h*64+s)] of a packed act buffer -> vt[(b*16+h)][s][t]
__global__ __launch_bounds__(256) void vtrans(
    const u16* __restrict__ src, u16* __restrict__ dst, int coloff, int ld)
{
  __shared__ u16 tile[64][65];
  const int t0 = blockIdx.x * 64, h = blockIdx.y, b = blockIdx.z;
  const int lr = threadIdx.x >> 4;
  const int lc = (threadIdx.x & 15) * 4;
#pragma unroll
  for (int i = 0; i < 64; i += 16) {
    const u16* sp = src + (size_t)(b * 1024 + t0 + lr + i) * ld + coloff + h * 64 + lc;
    const uint2 v = *(const uint2*)sp;
    tile[lr + i][lc + 0] = (u16)(v.x & 0xffff);
    tile[lr + i][lc + 1] = (u16)(v.x >> 16);
    tile[lr + i][lc + 2] = (u16)(v.y & 0xffff);
    tile[lr + i][lc + 3] = (u16)(v.y >> 16);
  }
  __syncthreads();
#pragma unroll
  for (int i = 0; i < 64; i += 16) {
    const int s = lr + i;
    uint2 ov;
    ov.x = (unsigned)tile[lc + 0][s] | ((unsigned)tile[lc + 1][s] << 16);
    ov.y = (unsigned)tile[lc + 2][s] | ((unsigned)tile[lc + 3][s] << 16);
    *(uint2*)(dst + (size_t)((b * 16 + h) * 64 + s) * 1024 + t0 + lc) = ov;
  }
}

// ---------------- inner causal flash attention ------------------------------
// grid (T/128, H, B), 512 thr (8 waves x 16 q-rows). scale = 1024^-0.5.
__global__ __launch_bounds__(512) void attn_inner(
    const u16* __restrict__ qkv, const u16* __restrict__ vt,
    u16* __restrict__ att)
{
  __shared__ u16 Kl[128 * 64];     // [kpos][s]
  __shared__ u16 Vl[64 * 128];     // [s][kpos]  (pre-transposed V)
  __shared__ u16 Pl[8 * 16 * 128]; // per-wave P [t][kpos]
  const int tb = blockIdx.x, h = blockIdx.y, b = blockIdx.z;
  const int tid = threadIdx.x, wid = tid >> 6, lane = tid & 63;
  const int col = lane & 15, kgr = lane >> 4;
  const float scale = 0.03125f;
  short8 qf[2];
  {
    const int trow = tb * 128 + wid * 16 + col;
    const u16* qp = qkv + (size_t)(b * 1024 + trow) * 3072 + h * 64 + kgr * 8;
    qf[0] = *(const short8*)qp;
    qf[1] = *(const short8*)(qp + 32);
  }
  f32x4 o[4] = {};
  float mrun[4], lrun[4];
#pragma unroll
  for (int r = 0; r < 4; ++r) { mrun[r] = -1e30f; lrun[r] = 0.f; }

  for (int kt = 0; kt <= tb * 128; kt += 128) {
#pragma unroll
    for (int i = 0; i < 2; ++i) {
      int e = i * 4096 + tid * 8;
      gload16(qkv + (size_t)(b * 1024 + kt + (e >> 6)) * 3072 + 1024 + h * 64 + (e & 63),
              &Kl[i * 4096 + wid * 512]);
      gload16(vt + (size_t)((b * 16 + h) * 64 + (e >> 7)) * 1024 + kt + (e & 127),
              &Vl[i * 4096 + wid * 512]);
    }
    __syncthreads();
    f32x4 s[8];
#pragma unroll
    for (int nt = 0; nt < 8; ++nt) {
      const short8 k0 = *(const short8*)&Kl[(nt * 16 + col) * 64 + kgr * 8];
      const short8 k1 = *(const short8*)&Kl[(nt * 16 + col) * 64 + 32 + kgr * 8];
      f32x4 a = {};
      a = MFMA16(qf[0], k0, a);
      a = MFMA16(qf[1], k1, a);
      s[nt] = a;
    }
    float mx[4];
#pragma unroll
    for (int r = 0; r < 4; ++r) mx[r] = -1e30f;
    const int tbase = tb * 128 + wid * 16 + kgr * 4;
#pragma unroll
    for (int nt = 0; nt < 8; ++nt) {
      const int kp = kt + nt * 16 + col;
#pragma unroll
      for (int r = 0; r < 4; ++r) {
        float v = s[nt][r] * scale;
        if (kp > tbase + r) v = -1e30f;
        s[nt][r] = v;
        mx[r] = fmaxf(mx[r], v);
      }
    }
#pragma unroll
    for (int r = 0; r < 4; ++r)
#pragma unroll
      for (int off = 1; off < 16; off <<= 1)
        mx[r] = fmaxf(mx[r], __shfl_xor(mx[r], off));
    float f[4], rs[4];
#pragma unroll
    for (int r = 0; r < 4; ++r) {
      const float mn = fmaxf(mrun[r], mx[r]);
      f[r] = __expf(mrun[r] - mn);
      mrun[r] = mn;
      rs[r] = 0.f;
    }
#pragma unroll
    for (int nt = 0; nt < 8; ++nt)
#pragma unroll
      for (int r = 0; r < 4; ++r) {
        const float p = __expf(s[nt][r] - mrun[r]);
        s[nt][r] = p;
        rs[r] += p;
      }
#pragma unroll
    for (int r = 0; r < 4; ++r) {
#pragma unroll
      for (int off = 1; off < 16; off <<= 1)
        rs[r] += __shfl_xor(rs[r], off);
      lrun[r] = lrun[r] * f[r] + rs[r];
    }
#pragma unroll
    for (int st = 0; st < 4; ++st)
#pragma unroll
      for (int r = 0; r < 4; ++r)
        o[st][r] *= f[r];
    u16* pw = &Pl[wid * 2048];
#pragma unroll
    for (int nt = 0; nt < 8; ++nt)
#pragma unroll
      for (int r = 0; r < 4; ++r)
        pw[(kgr * 4 + r) * 128 + nt * 16 + col] = f2bf(s[nt][r]);
#pragma unroll
    for (int ks = 0; ks < 4; ++ks) {
      const short8 pa = *(const short8*)&pw[col * 128 + ks * 32 + kgr * 8];
#pragma unroll
      for (int st = 0; st < 4; ++st) {
        const short8 vb = *(const short8*)&Vl[(st * 16 + col) * 128 + ks * 32 + kgr * 8];
        o[st] = MFMA16(pa, vb, o[st]);
      }
    }
    __syncthreads();
  }
#pragma unroll
  for (int r = 0; r < 4; ++r) {
    const float inv = 1.f / lrun[r];
    const int t = tb * 128 + wid * 16 + kgr * 4 + r;
#pragma unroll
    for (int st = 0; st < 4; ++st)
      att[(size_t)(b * 1024 + t) * 1024 + h * 64 + st * 16 + col] =
          f2bf(o[st][r] * inv);
  }
}

// ---------------- compressing cross attention -------------------------------
// grid (H, B), 512 thr. out[b,r,h,s] = sum_t softmax_r(q@kk^T * scale)[t,r] * v[t,s]
__global__ __launch_bounds__(512) void attn_cross(
    const u16* __restrict__ qv, const u16* __restrict__ kk,
    const u16* __restrict__ vt, u16* __restrict__ outc)
{
  __shared__ u16 KKl[256 * 64];   // [r][s]
  __shared__ u16 Vl[64 * 128];    // [s][t]
  __shared__ u16 PTl[256 * 128];  // P^T [r][t_local]
  const int h = blockIdx.x, b = blockIdx.y;
  const int tid = threadIdx.x, wid = tid >> 6, lane = tid & 63;
  const int col = lane & 15, kgr = lane >> 4;
  const float scale = 0.03125f;
#pragma unroll
  for (int i = 0; i < 4; ++i) {
    int e = i * 4096 + tid * 8;
    gload16(kk + (size_t)(e >> 6) * 1024 + h * 64 + (e & 63), &KKl[i * 4096 + wid * 512]);
  }
  f32x4 oacc[2][4] = {};
  for (int tt = 0; tt < 8; ++tt) {
    const int t0 = tt * 128;
#pragma unroll
    for (int i = 0; i < 2; ++i) {
      int e = i * 4096 + tid * 8;
      gload16(vt + (size_t)((b * 16 + h) * 64 + (e >> 7)) * 1024 + t0 + (e & 127),
              &Vl[i * 4096 + wid * 512]);
    }
    short8 qf0, qf1;
    {
      const int trow = t0 + wid * 16 + col;
      const u16* qp = qv + (size_t)(b * 1024 + trow) * 2048 + h * 64 + kgr * 8;
      qf0 = *(const short8*)qp;
      qf1 = *(const short8*)(qp + 32);
    }
    __syncthreads();
    f32x4 s[16];
#pragma unroll
    for (int rt = 0; rt < 16; ++rt) {
      const short8 k0 = *(const short8*)&KKl[(rt * 16 + col) * 64 + kgr * 8];
      const short8 k1 = *(const short8*)&KKl[(rt * 16 + col) * 64 + 32 + kgr * 8];
      f32x4 a = {};
      a = MFMA16(qf0, k0, a);
      a = MFMA16(qf1, k1, a);
      s[rt] = a;
    }
    float mx[4];
#pragma unroll
    for (int r = 0; r < 4; ++r) mx[r] = -1e30f;
    const int tbase = t0 + wid * 16 + kgr * 4;
#pragma unroll
    for (int rt = 0; rt < 16; ++rt) {
      const int rp = rt * 16 + col;
#pragma unroll
      for (int r = 0; r < 4; ++r) {
        float v = s[rt][r] * scale;
        if (rp > tbase + r) v = -1e30f;
        s[rt][r] = v;
        mx[r] = fmaxf(mx[r], v);
      }
    }
#pragma unroll
    for (int r = 0; r < 4; ++r)
#pragma unroll
      for (int off = 1; off < 16; off <<= 1)
        mx[r] = fmaxf(mx[r], __shfl_xor(mx[r], off));
    float sm[4];
#pragma unroll
    for (int r = 0; r < 4; ++r) sm[r] = 0.f;
#pragma unroll
    for (int rt = 0; rt < 16; ++rt)
#pragma unroll
      for (int r = 0; r < 4; ++r) {
        const float p = __expf(s[rt][r] - mx[r]);
        s[rt][r] = p;
        sm[r] += p;
      }
#pragma unroll
    for (int r = 0; r < 4; ++r) {
#pragma unroll
      for (int off = 1; off < 16; off <<= 1)
        sm[r] += __shfl_xor(sm[r], off);
      sm[r] = 1.f / sm[r];
    }
#pragma unroll
    for (int rt = 0; rt < 16; ++rt)
#pragma unroll
      for (int r = 0; r < 4; ++r)
        PTl[(rt * 16 + col) * 128 + wid * 16 + kgr * 4 + r] = f2bf(s[rt][r] * sm[r]);
    __syncthreads();
#pragma unroll
    for (int rr = 0; rr < 2; ++rr) {
      const int rb = (wid * 2 + rr) * 16;
#pragma unroll
      for (int ks = 0; ks < 4; ++ks) {
        const short8 pa = *(const short8*)&PTl[(rb + col) * 128 + ks * 32 + kgr * 8];
#pragma unroll
        for (int st = 0; st < 4; ++st) {
          const short8 vb = *(const short8*)&Vl[(st * 16 + col) * 128 + ks * 32 + kgr * 8];
          oacc[rr][st] = MFMA16(pa, vb, oacc[rr][st]);
        }
      }
    }
    __syncthreads();
  }
#pragma unroll
  for (int rr = 0; rr < 2; ++rr)
#pragma unroll
    for (int st = 0; st < 4; ++st)
#pragma unroll
      for (int r = 0; r < 4; ++r) {
        const int rpos = (wid * 2 + rr) * 16 + kgr * 4 + r;
        outc[(size_t)(b * 256 + rpos) * 1024 + h * 64 + st * 16 + col] =
            f2bf(oacc[rr][st][r]);
      }
}

// ---------------- host orchestration ----------------------------------------
extern "C" void kernel_launch(void* const* d_in, const int* in_sizes, int n_in,
                              void* d_out, int out_size, void* d_ws, size_t ws_size,
                              hipStream_t stream)
{
  const float* x     = (const float*)d_in[0];
  const float* pos   = (const float*)d_in[1];
  const float* bln1g = (const float*)d_in[2];
  const float* bln1b = (const float*)d_in[3];
  const float* bwq   = (const float*)d_in[4];
  const float* bwk   = (const float*)d_in[5];
  const float* bwv   = (const float*)d_in[6];
  const float* bwo   = (const float*)d_in[7];
  const float* bbo   = (const float*)d_in[8];
  const float* bln2g = (const float*)d_in[9];
  const float* bln2b = (const float*)d_in[10];
  const float* bw1   = (const float*)d_in[11];
  const float* bb1   = (const float*)d_in[12];
  const float* bw2   = (const float*)d_in[13];
  const float* bb2   = (const float*)d_in[14];
  const float* ln1g  = (const float*)d_in[15];
  const float* ln1b  = (const float*)d_in[16];
  const float* cwq   = (const float*)d_in[17];
  const float* cwk   = (const float*)d_in[18];
  const float* cwv   = (const float*)d_in[19];
  const float* cwo   = (const float*)d_in[20];
  const float* cbo   = (const float*)d_in[21];
  const float* cln2g = (const float*)d_in[22];
  const float* cln2b = (const float*)d_in[23];
  const float* fw1   = (const float*)d_in[24];
  const float* fb1   = (const float*)d_in[25];
  const float* fw2   = (const float*)d_in[26];
  const float* fb2   = (const float*)d_in[27];

  char* ws = (char*)d_ws;
  size_t off = 0;
  auto alloc = [&](size_t bytes) -> void* {
    void* p = ws + off; off += (bytes + 255) & ~(size_t)255; return p;
  };
  u16* wqkv_t = (u16*)alloc((size_t)3072 * 1024 * 2);
  u16* wo_t   = (u16*)alloc((size_t)1024 * 1024 * 2);
  u16* w1_t   = (u16*)alloc((size_t)4096 * 1024 * 2);
  u16* w2_t   = (u16*)alloc((size_t)1024 * 4096 * 2);
  u16* cwqv_t = (u16*)alloc((size_t)2048 * 1024 * 2);
  u16* cwk_t  = (u16*)alloc((size_t)1024 * 1024 * 2);
  u16* cwo_t  = (u16*)alloc((size_t)1024 * 1024 * 2);
  u16* fw1_t  = (u16*)alloc((size_t)4096 * 1024 * 2);
  u16* fw2_t  = (u16*)alloc((size_t)1024 * 4096 * 2);
  u16* pos_bf = (u16*)alloc((size_t)256 * 1024 * 2);
  u16* kkb    = (u16*)alloc((size_t)256 * 1024 * 2);
  u16* act_ln = (u16*)alloc((size_t)8192 * 1024 * 2);
  u16* qkv    = (u16*)alloc((size_t)8192 * 3072 * 2);
  u16* att    = (u16*)alloc((size_t)8192 * 1024 * 2);
  u16* ffb    = (u16*)alloc((size_t)8192 * 4096 * 2);
  float* yb   = (float*)alloc((size_t)8192 * 1024 * 4);
  if (ws_size < off) return;  // insufficient workspace -> visible failure
  // aliases (lifetimes disjoint):
  float* x2   = (float*)qkv;  // qkv dead after attn_inner
  u16*   qv   = qkv;          // cross q/v reuses qkv region
  u16*   vt   = ffb;          // V-transpose lives in ffb head (dead around it)
  u16*   outc = att;          // att dead after wo-proj
  float* zb   = yb;           // yb dead after FFN residual
  float* outp = (float*)d_out;

  const dim3 B256(256), B512(512);
  // weight packing
  pack_head_w<<<dim3(2, 32, 16), B256, 0, stream>>>(bwq, wqkv_t);
  pack_head_w<<<dim3(2, 32, 16), B256, 0, stream>>>(bwk, wqkv_t + 1024 * 1024);
  pack_head_w<<<dim3(2, 32, 16), B256, 0, stream>>>(bwv, wqkv_t + 2048 * 1024);
  transpose_w<<<dim3(32, 32),  B256, 0, stream>>>(bwo, wo_t, 1024, 1024);
  transpose_w<<<dim3(128, 32), B256, 0, stream>>>(bw1, w1_t, 1024, 4096);
  transpose_w<<<dim3(32, 128), B256, 0, stream>>>(bw2, w2_t, 4096, 1024);
  pack_head_w<<<dim3(2, 32, 16), B256, 0, stream>>>(cwq, cwqv_t);
  pack_head_w<<<dim3(2, 32, 16), B256, 0, stream>>>(cwv, cwqv_t + 1024 * 1024);
  pack_head_w<<<dim3(2, 32, 16), B256, 0, stream>>>(cwk, cwk_t);
  transpose_w<<<dim3(32, 32),  B256, 0, stream>>>(cwo, cwo_t, 1024, 1024);
  transpose_w<<<dim3(128, 32), B256, 0, stream>>>(fw1, fw1_t, 1024, 4096);
  transpose_w<<<dim3(32, 128), B256, 0, stream>>>(fw2, fw2_t, 4096, 1024);
  cvt_bf16<<<dim3(256), B256, 0, stream>>>(pos, pos_bf);

  // ---- inner standard block ----
  ln_rows<<<dim3(8192), B256, 0, stream>>>(x, bln1g, bln1b, act_ln);
  gemm_bt<<<dim3(64, 24), B256, 0, stream>>>(act_ln, wqkv_t, nullptr, qkv,
      nullptr, nullptr, nullptr, 8192, 3072, 1024, 0);
  vtrans<<<dim3(16, 16, 8), B256, 0, stream>>>(qkv, vt, 2048, 3072);
  attn_inner<<<dim3(8, 16, 8), B512, 0, stream>>>(qkv, vt, att);
  gemm_bt<<<dim3(64, 8), B256, 0, stream>>>(att, wo_t, yb, nullptr,
      bbo, x, nullptr, 8192, 1024, 1024, 0);                 // y = x + att@Wo+bo
  ln_rows<<<dim3(8192), B256, 0, stream>>>(yb, bln2g, bln2b, act_ln);
  gemm_bt<<<dim3(64, 32), B256, 0, stream>>>(act_ln, w1_t, nullptr, ffb,
      bb1, nullptr, nullptr, 8192, 4096, 1024, 1);           // relu(h2@W1+b1)
  gemm_bt<<<dim3(64, 8), B256, 0, stream>>>(ffb, w2_t, x2, nullptr,
      bb2, yb, x, 8192, 1024, 4096, 0);                      // x2 = x + y + ffn

  // ---- compressing cross-attention ----
  ln_rows<<<dim3(8192), B256, 0, stream>>>(x2, ln1g, ln1b, act_ln);
  gemm_bt<<<dim3(64, 16), B256, 0, stream>>>(act_ln, cwqv_t, nullptr, qv,
      nullptr, nullptr, nullptr, 8192, 2048, 1024, 0);       // [q|v]
  gemm_bt<<<dim3(2, 8), B256, 0, stream>>>(pos_bf, cwk_t, nullptr, kkb,
      nullptr, nullptr, nullptr, 256, 1024, 1024, 0);        // kk
  vtrans<<<dim3(16, 16, 8), B256, 0, stream>>>(qv, vt, 1024, 2048);
  attn_cross<<<dim3(16, 8), B512, 0, stream>>>(qv, kkb, vt, outc);
  gemm_bt<<<dim3(16, 8), B256, 0, stream>>>(outc, cwo_t, zb, nullptr,
      cbo, nullptr, nullptr, 2048, 1024, 1024, 0);           // z = out@Wo+bo

  // ---- final FFN ----
  ln_rows<<<dim3(2048), B256, 0, stream>>>(zb, cln2g, cln2b, act_ln);
  gemm_bt<<<dim3(16, 32), B256, 0, stream>>>(act_ln, fw1_t, nullptr, ffb,
      fb1, nullptr, nullptr, 2048, 4096, 1024, 1);
  gemm_bt<<<dim3(16, 8), B256, 0, stream>>>(ffb, fw2_t, outp, nullptr,
      fb2, zb, nullptr, 2048, 1024, 4096, 0);                // out = z + ffn
}

// Round 2
// 1005.552 us; speedup vs baseline: 1.0124x; 1.0124x over previous
//
#include <hip/hip_runtime.h>
#include <stdint.h>

typedef unsigned short u16;
typedef __attribute__((ext_vector_type(8))) short short8;
typedef __attribute__((ext_vector_type(4))) float f32x4;

#define MFMA16(A,B,C) __builtin_amdgcn_mfma_f32_16x16x32_bf16(A,B,C,0,0,0)

static __device__ __forceinline__ u16 f2bf(float f) {
  union { float f; unsigned u; } v; v.f = f;
  unsigned r = v.u + 0x7FFFu + ((v.u >> 16) & 1u);
  return (u16)(r >> 16);
}

static __device__ __forceinline__ void gload16(const void* g, void* l) {
  __builtin_amdgcn_global_load_lds(
      (const __attribute__((address_space(1))) void*)(uintptr_t)g,
      (__attribute__((address_space(3))) void*)(uint32_t)(uintptr_t)l,
      16, 0, 0);
}

// ============ 256x256 8-phase bf16 GEMM: C[M,N] = A[M,K] @ Wt[N,K]^T ========
// 512 thr = 8 waves (2m x 4n), per-wave 128x64 out. BK=64, double-buffered
// 128KB LDS [mat][buf][khalf][256][32] with slot^=(row>>1)&3 swizzle
// (pre-swizzled global source, swizzled ds_read -> uniform bank spread).
// Counted vmcnt(4) once per K-tile; raw s_barriers; setprio around MFMA.
#define PHASE(BUFO, MH, KH, STAGE_STMT, TAIL_STMT) do { \
  short8 af_[4], bf_[4]; \
  _Pragma("unroll") \
  for (int mf = 0; mf < 4; ++mf) { \
    const int r = wm0 + ((MH) * 4 + mf) * 16 + colL; \
    af_[mf] = *(const short8*)&lds[(BUFO) + ((KH) << 13) + r * 32 + ((kgr ^ ((r >> 1) & 3)) << 3)]; \
  } \
  _Pragma("unroll") \
  for (int nf = 0; nf < 4; ++nf) { \
    const int r = wn0 + nf * 16 + colL; \
    bf_[nf] = *(const short8*)&lds[(BUFO) + 16384 + ((KH) << 13) + r * 32 + ((kgr ^ ((r >> 1) & 3)) << 3)]; \
  } \
  STAGE_STMT; \
  __builtin_amdgcn_s_barrier(); \
  asm volatile("s_waitcnt lgkmcnt(0)" ::: "memory"); \
  __builtin_amdgcn_sched_barrier(0); \
  __builtin_amdgcn_s_setprio(1); \
  _Pragma("unroll") \
  for (int mf = 0; mf < 4; ++mf) \
    _Pragma("unroll") \
    for (int nf = 0; nf < 4; ++nf) \
      acc[(MH) * 4 + mf][nf] = MFMA16(af_[mf], bf_[nf], acc[(MH) * 4 + mf][nf]); \
  __builtin_amdgcn_s_setprio(0); \
  __builtin_amdgcn_sched_barrier(0); \
  TAIL_STMT; \
  __builtin_amdgcn_s_barrier(); \
} while (0)

__global__ __launch_bounds__(512, 1) void gemm256(
    const u16* __restrict__ A, const u16* __restrict__ Wt,
    float* __restrict__ Cf, u16* __restrict__ Cb,
    const float* __restrict__ bias,
    const float* __restrict__ res1, const float* __restrict__ res2,
    int M, int N, int K, int relu)
{
  __shared__ u16 lds[65536];  // 128 KiB
  const int tid = threadIdx.x;
  const int wid = tid >> 6, lane = tid & 63;
  const int colL = lane & 15, kgr = lane >> 4;
  const int wm0 = (wid & 1) * 128, wn0 = (wid >> 1) * 64;
  const int m0 = blockIdx.x * 256, n0 = blockIdx.y * 256;
  const int NT = K >> 6;
  f32x4 acc[8][4] = {};

  // stage one unit = (mat, K-tile t_, k-half): 256 rows x 32 cols, 2 loads/thr.
  // LDS elem offset: buf*32768 + mat*16384 + kh*8192 (linear dest);
  // global source pre-swizzled: slot ^ ((row>>1)&3).
  auto stage = [&](const u16* src, int row0, int t_, int mat, int kh) {
    const size_t kb = (size_t)t_ * 64 + kh * 32;
    const int base = ((t_ & 1) << 15) + (mat << 14) + (kh << 13);
#pragma unroll
    for (int i = 0; i < 2; ++i) {
      const int c = i * 512 + tid;
      const int row = c >> 2, slot = c & 3;
      gload16(src + (size_t)(row0 + row) * K + kb + ((slot ^ ((row >> 1) & 3)) << 3),
              &lds[base + ((i * 512 + wid * 64) << 3)]);
    }
  };

  // prologue: tile0 (4 units) + tile1 k0 (2 units); drain tile0, keep 4 in flight
  stage(A,  m0, 0, 0, 0); stage(Wt, n0, 0, 1, 0);
  stage(A,  m0, 0, 0, 1); stage(Wt, n0, 0, 1, 1);
  stage(A,  m0, 1, 0, 0); stage(Wt, n0, 1, 1, 0);
  asm volatile("s_waitcnt vmcnt(4)" ::: "memory");
  __builtin_amdgcn_s_barrier();

  for (int t = 0; t < NT; ++t) {
    const int bufo = (t & 1) << 15;
    PHASE(bufo, 0, 0, if (t + 1 < NT) stage(A,  m0, t + 1, 0, 1), );
    PHASE(bufo, 1, 0, if (t + 1 < NT) stage(Wt, n0, t + 1, 1, 1), );
    PHASE(bufo, 0, 1, if (t + 2 < NT) stage(A,  m0, t + 2, 0, 0), );
    PHASE(bufo, 1, 1, if (t + 2 < NT) stage(Wt, n0, t + 2, 1, 0),
          if (t < NT - 2) { asm volatile("s_waitcnt vmcnt(4)" ::: "memory"); }
          else            { asm volatile("s_waitcnt vmcnt(0)" ::: "memory"); } );
  }

#pragma unroll
  for (int mf = 0; mf < 8; ++mf) {
#pragma unroll
    for (int nf = 0; nf < 4; ++nf) {
      const int n = n0 + wn0 + nf * 16 + colL;
      const float bv = bias ? bias[n] : 0.f;
#pragma unroll
      for (int rr = 0; rr < 4; ++rr) {
        const int m = m0 + wm0 + mf * 16 + kgr * 4 + rr;
        const size_t off = (size_t)m * N + n;
        float v = acc[mf][nf][rr] + bv;
        if (res1) v += res1[off];
        if (res2) v += res2[off];
        if (relu) v = fmaxf(v, 0.f);
        if (Cf) Cf[off] = v; else Cb[off] = f2bf(v);
      }
    }
  }
}

// ---------------- generic bf16 GEMM (128x128), for small shapes -------------
__global__ __launch_bounds__(256) void gemm_bt(
    const u16* __restrict__ A, const u16* __restrict__ Wt,
    float* __restrict__ Cf, u16* __restrict__ Cb,
    const float* __restrict__ bias,
    const float* __restrict__ res1, const float* __restrict__ res2,
    int M, int N, int K, int relu)
{
  __shared__ u16 lsA[128 * 32];
  __shared__ u16 lsB[128 * 32];
  const int tid = threadIdx.x;
  const int wid = tid >> 6, lane = tid & 63;
  const int col = lane & 15, kgr = lane >> 4;
  const int m0 = blockIdx.x * 128, n0 = blockIdx.y * 128;
  const int wm = (wid >> 1) * 64, wn = (wid & 1) * 64;
  f32x4 acc[4][4] = {};
  const int nk = K >> 5;
  for (int kt = 0; kt < nk; ++kt) {
    const int k0 = kt << 5;
#pragma unroll
    for (int i = 0; i < 2; ++i) {
      int e = i * 2048 + tid * 8;
      gload16(A  + (size_t)(m0 + (e >> 5)) * K + k0 + (e & 31), &lsA[i * 2048 + wid * 512]);
      gload16(Wt + (size_t)(n0 + (e >> 5)) * K + k0 + (e & 31), &lsB[i * 2048 + wid * 512]);
    }
    __syncthreads();
    short8 af[4], bfr[4];
#pragma unroll
    for (int t = 0; t < 4; ++t) {
      af[t]  = *(const short8*)&lsA[(wm + t * 16 + col) * 32 + kgr * 8];
      bfr[t] = *(const short8*)&lsB[(wn + t * 16 + col) * 32 + kgr * 8];
    }
#pragma unroll
    for (int mt = 0; mt < 4; ++mt)
#pragma unroll
      for (int nt = 0; nt < 4; ++nt)
        acc[mt][nt] = MFMA16(af[mt], bfr[nt], acc[mt][nt]);
    __syncthreads();
  }
#pragma unroll
  for (int nt = 0; nt < 4; ++nt) {
    const int n = n0 + wn + nt * 16 + col;
    const float bv = bias ? bias[n] : 0.f;
#pragma unroll
    for (int mt = 0; mt < 4; ++mt) {
#pragma unroll
      for (int r = 0; r < 4; ++r) {
        const int m = m0 + wm + mt * 16 + kgr * 4 + r;
        const size_t off = (size_t)m * N + n;
        float v = acc[mt][nt][r] + bv;
        if (res1) v += res1[off];
        if (res2) v += res2[off];
        if (relu) v = fmaxf(v, 0.f);
        if (Cf) Cf[off] = v; else Cb[off] = f2bf(v);
      }
    }
  }
}

// ---------------- LayerNorm (fp32 in, bf16 out), one row (D=1024) per block --
__global__ __launch_bounds__(256) void ln_rows(
    const float* __restrict__ x, const float* __restrict__ g,
    const float* __restrict__ bt, u16* __restrict__ out)
{
  const int row = blockIdx.x, tid = threadIdx.x;
  const float4 v = ((const float4*)(x + (size_t)row * 1024))[tid];
  float s  = v.x + v.y + v.z + v.w;
  float ss = v.x * v.x + v.y * v.y + v.z * v.z + v.w * v.w;
#pragma unroll
  for (int off = 32; off; off >>= 1) {
    s  += __shfl_xor(s, off);
    ss += __shfl_xor(ss, off);
  }
  __shared__ float red[8];
  const int wid = tid >> 6, lane = tid & 63;
  if (lane == 0) { red[wid] = s; red[4 + wid] = ss; }
  __syncthreads();
  s  = red[0] + red[1] + red[2] + red[3];
  ss = red[4] + red[5] + red[6] + red[7];
  const float mean = s * 0.0009765625f;
  const float var  = ss * 0.0009765625f - mean * mean;
  const float rstd = rsqrtf(var + 1e-5f);
  const float4 gg = ((const float4*)g)[tid];
  const float4 bb = ((const float4*)bt)[tid];
  uint2 ov;
  ov.x = (unsigned)f2bf((v.x - mean) * rstd * gg.x + bb.x) |
         ((unsigned)f2bf((v.y - mean) * rstd * gg.y + bb.y) << 16);
  ov.y = (unsigned)f2bf((v.z - mean) * rstd * gg.z + bb.z) |
         ((unsigned)f2bf((v.w - mean) * rstd * gg.w + bb.w) << 16);
  *(uint2*)(out + (size_t)row * 1024 + tid * 4) = ov;
}

// ---------------- weight packing --------------------------------------------
__global__ __launch_bounds__(256) void transpose_w(
    const float* __restrict__ in, u16* __restrict__ out, int R, int C)
{
  __shared__ float t[32][33];
  const int c0 = blockIdx.x * 32, r0 = blockIdx.y * 32;
  const int tx = threadIdx.x & 31, ty = threadIdx.x >> 5;
#pragma unroll
  for (int i = 0; i < 32; i += 8)
    t[ty + i][tx] = in[(size_t)(r0 + ty + i) * C + c0 + tx];
  __syncthreads();
#pragma unroll
  for (int i = 0; i < 32; i += 8)
    out[(size_t)(c0 + ty + i) * R + r0 + tx] = f2bf(t[tx][ty + i]);
}

__global__ __launch_bounds__(256) void pack_head_w(
    const float* __restrict__ w, u16* __restrict__ out)
{
  __shared__ float t[32][33];
  const int h = blockIdx.z;
  const int s0 = blockIdx.x * 32, c0 = blockIdx.y * 32;
  const int tx = threadIdx.x & 31, ty = threadIdx.x >> 5;
#pragma unroll
  for (int i = 0; i < 32; i += 8)
    t[ty + i][tx] = w[((size_t)h * 1024 + c0 + ty + i) * 64 + s0 + tx];
  __syncthreads();
#pragma unroll
  for (int i = 0; i < 32; i += 8)
    out[((size_t)h * 64 + s0 + ty + i) * 1024 + c0 + tx] = f2bf(t[tx][ty + i]);
}

__global__ __launch_bounds__(256) void cvt_bf16(
    const float* __restrict__ in, u16* __restrict__ out)
{
  const int i = blockIdx.x * blockDim.x + threadIdx.x;
  const float4 v = ((const float4*)in)[i];
  uint2 ov;
  ov.x = (unsigned)f2bf(v.x) | ((unsigned)f2bf(v.y) << 16);
  ov.y = (unsigned)f2bf(v.z) | ((unsigned)f2bf(v.w) << 16);
  *(uint2*)(out + (size_t)i * 4) = ov;
}

__global__ __launch_bounds__(256) void vtrans(
    const u16* __restrict__ src, u16* __restrict__ dst, int coloff, int ld)
{
  __shared__ u16 tile[64][65];
  const int t0 = blockIdx.x * 64, h = blockIdx.y, b = blockIdx.z;
  const int lr = threadIdx.x >> 4;
  const int lc = (threadIdx.x & 15) * 4;
#pragma unroll
  for (int i = 0; i < 64; i += 16) {
    const u16* sp = src + (size_t)(b * 1024 + t0 + lr + i) * ld + coloff + h * 64 + lc;
    const uint2 v = *(const uint2*)sp;
    tile[lr + i][lc + 0] = (u16)(v.x & 0xffff);
    tile[lr + i][lc + 1] = (u16)(v.x >> 16);
    tile[lr + i][lc + 2] = (u16)(v.y & 0xffff);
    tile[lr + i][lc + 3] = (u16)(v.y >> 16);
  }
  __syncthreads();
#pragma unroll
  for (int i = 0; i < 64; i += 16) {
    const int s = lr + i;
    uint2 ov;
    ov.x = (unsigned)tile[lc + 0][s] | ((unsigned)tile[lc + 1][s] << 16);
    ov.y = (unsigned)tile[lc + 2][s] | ((unsigned)tile[lc + 3][s] << 16);
    *(uint2*)(dst + (size_t)((b * 16 + h) * 64 + s) * 1024 + t0 + lc) = ov;
  }
}

// ---------------- inner causal flash attention ------------------------------
__global__ __launch_bounds__(512) void attn_inner(
    const u16* __restrict__ qkv, const u16* __restrict__ vt,
    u16* __restrict__ att)
{
  __shared__ u16 Kl[128 * 64];
  __shared__ u16 Vl[64 * 128];
  __shared__ u16 Pl[8 * 16 * 128];
  const int tb = blockIdx.x, h = blockIdx.y, b = blockIdx.z;
  const int tid = threadIdx.x, wid = tid >> 6, lane = tid & 63;
  const int col = lane & 15, kgr = lane >> 4;
  const float scale = 0.03125f;
  short8 qf[2];
  {
    const int trow = tb * 128 + wid * 16 + col;
    const u16* qp = qkv + (size_t)(b * 1024 + trow) * 3072 + h * 64 + kgr * 8;
    qf[0] = *(const short8*)qp;
    qf[1] = *(const short8*)(qp + 32);
  }
  f32x4 o[4] = {};
  float mrun[4], lrun[4];
#pragma unroll
  for (int r = 0; r < 4; ++r) { mrun[r] = -1e30f; lrun[r] = 0.f; }

  for (int kt = 0; kt <= tb * 128; kt += 128) {
#pragma unroll
    for (int i = 0; i < 2; ++i) {
      int e = i * 4096 + tid * 8;
      gload16(qkv + (size_t)(b * 1024 + kt + (e >> 6)) * 3072 + 1024 + h * 64 + (e & 63),
              &Kl[i * 4096 + wid * 512]);
      gload16(vt + (size_t)((b * 16 + h) * 64 + (e >> 7)) * 1024 + kt + (e & 127),
              &Vl[i * 4096 + wid * 512]);
    }
    __syncthreads();
    f32x4 s[8];
#pragma unroll
    for (int nt = 0; nt < 8; ++nt) {
      const short8 k0 = *(const short8*)&Kl[(nt * 16 + col) * 64 + kgr * 8];
      const short8 k1 = *(const short8*)&Kl[(nt * 16 + col) * 64 + 32 + kgr * 8];
      f32x4 a = {};
      a = MFMA16(qf[0], k0, a);
      a = MFMA16(qf[1], k1, a);
      s[nt] = a;
    }
    float mx[4];
#pragma unroll
    for (int r = 0; r < 4; ++r) mx[r] = -1e30f;
    const int tbase = tb * 128 + wid * 16 + kgr * 4;
#pragma unroll
    for (int nt = 0; nt < 8; ++nt) {
      const int kp = kt + nt * 16 + col;
#pragma unroll
      for (int r = 0; r < 4; ++r) {
        float v = s[nt][r] * scale;
        if (kp > tbase + r) v = -1e30f;
        s[nt][r] = v;
        mx[r] = fmaxf(mx[r], v);
      }
    }
#pragma unroll
    for (int r = 0; r < 4; ++r)
#pragma unroll
      for (int off = 1; off < 16; off <<= 1)
        mx[r] = fmaxf(mx[r], __shfl_xor(mx[r], off));
    float f[4], rs[4];
#pragma unroll
    for (int r = 0; r < 4; ++r) {
      const float mn = fmaxf(mrun[r], mx[r]);
      f[r] = __expf(mrun[r] - mn);
      mrun[r] = mn;
      rs[r] = 0.f;
    }
#pragma unroll
    for (int nt = 0; nt < 8; ++nt)
#pragma unroll
      for (int r = 0; r < 4; ++r) {
        const float p = __expf(s[nt][r] - mrun[r]);
        s[nt][r] = p;
        rs[r] += p;
      }
#pragma unroll
    for (int r = 0; r < 4; ++r) {
#pragma unroll
      for (int off = 1; off < 16; off <<= 1)
        rs[r] += __shfl_xor(rs[r], off);
      lrun[r] = lrun[r] * f[r] + rs[r];
    }
#pragma unroll
    for (int st = 0; st < 4; ++st)
#pragma unroll
      for (int r = 0; r < 4; ++r)
        o[st][r] *= f[r];
    u16* pw = &Pl[wid * 2048];
#pragma unroll
    for (int nt = 0; nt < 8; ++nt)
#pragma unroll
      for (int r = 0; r < 4; ++r)
        pw[(kgr * 4 + r) * 128 + nt * 16 + col] = f2bf(s[nt][r]);
#pragma unroll
    for (int ks = 0; ks < 4; ++ks) {
      const short8 pa = *(const short8*)&pw[col * 128 + ks * 32 + kgr * 8];
#pragma unroll
      for (int st = 0; st < 4; ++st) {
        const short8 vb = *(const short8*)&Vl[(st * 16 + col) * 128 + ks * 32 + kgr * 8];
        o[st] = MFMA16(pa, vb, o[st]);
      }
    }
    __syncthreads();
  }
#pragma unroll
  for (int r = 0; r < 4; ++r) {
    const float inv = 1.f / lrun[r];
    const int t = tb * 128 + wid * 16 + kgr * 4 + r;
#pragma unroll
    for (int st = 0; st < 4; ++st)
      att[(size_t)(b * 1024 + t) * 1024 + h * 64 + st * 16 + col] =
          f2bf(o[st][r] * inv);
  }
}

// ---------------- compressing cross attention -------------------------------
__global__ __launch_bounds__(512) void attn_cross(
    const u16* __restrict__ qv, const u16* __restrict__ kk,
    const u16* __restrict__ vt, u16* __restrict__ outc)
{
  __shared__ u16 KKl[256 * 64];
  __shared__ u16 Vl[64 * 128];
  __shared__ u16 PTl[256 * 128];
  const int h = blockIdx.x, b = blockIdx.y;
  const int tid = threadIdx.x, wid = tid >> 6, lane = tid & 63;
  const int col = lane & 15, kgr = lane >> 4;
  const float scale = 0.03125f;
#pragma unroll
  for (int i = 0; i < 4; ++i) {
    int e = i * 4096 + tid * 8;
    gload16(kk + (size_t)(e >> 6) * 1024 + h * 64 + (e & 63), &KKl[i * 4096 + wid * 512]);
  }
  f32x4 oacc[2][4] = {};
  for (int tt = 0; tt < 8; ++tt) {
    const int t0 = tt * 128;
#pragma unroll
    for (int i = 0; i < 2; ++i) {
      int e = i * 4096 + tid * 8;
      gload16(vt + (size_t)((b * 16 + h) * 64 + (e >> 7)) * 1024 + t0 + (e & 127),
              &Vl[i * 4096 + wid * 512]);
    }
    short8 qf0, qf1;
    {
      const int trow = t0 + wid * 16 + col;
      const u16* qp = qv + (size_t)(b * 1024 + trow) * 2048 + h * 64 + kgr * 8;
      qf0 = *(const short8*)qp;
      qf1 = *(const short8*)(qp + 32);
    }
    __syncthreads();
    f32x4 s[16];
#pragma unroll
    for (int rt = 0; rt < 16; ++rt) {
      const short8 k0 = *(const short8*)&KKl[(rt * 16 + col) * 64 + kgr * 8];
      const short8 k1 = *(const short8*)&KKl[(rt * 16 + col) * 64 + 32 + kgr * 8];
      f32x4 a = {};
      a = MFMA16(qf0, k0, a);
      a = MFMA16(qf1, k1, a);
      s[rt] = a;
    }
    float mx[4];
#pragma unroll
    for (int r = 0; r < 4; ++r) mx[r] = -1e30f;
    const int tbase = t0 + wid * 16 + kgr * 4;
#pragma unroll
    for (int rt = 0; rt < 16; ++rt) {
      const int rp = rt * 16 + col;
#pragma unroll
      for (int r = 0; r < 4; ++r) {
        float v = s[rt][r] * scale;
        if (rp > tbase + r) v = -1e30f;
        s[rt][r] = v;
        mx[r] = fmaxf(mx[r], v);
      }
    }
#pragma unroll
    for (int r = 0; r < 4; ++r)
#pragma unroll
      for (int off = 1; off < 16; off <<= 1)
        mx[r] = fmaxf(mx[r], __shfl_xor(mx[r], off));
    float sm[4];
#pragma unroll
    for (int r = 0; r < 4; ++r) sm[r] = 0.f;
#pragma unroll
    for (int rt = 0; rt < 16; ++rt)
#pragma unroll
      for (int r = 0; r < 4; ++r) {
        const float p = __expf(s[rt][r] - mx[r]);
        s[rt][r] = p;
        sm[r] += p;
      }
#pragma unroll
    for (int r = 0; r < 4; ++r) {
#pragma unroll
      for (int off = 1; off < 16; off <<= 1)
        sm[r] += __shfl_xor(sm[r], off);
      sm[r] = 1.f / sm[r];
    }
#pragma unroll
    for (int rt = 0; rt < 16; ++rt)
#pragma unroll
      for (int r = 0; r < 4; ++r)
        PTl[(rt * 16 + col) * 128 + wid * 16 + kgr * 4 + r] = f2bf(s[rt][r] * sm[r]);
    __syncthreads();
#pragma unroll
    for (int rr = 0; rr < 2; ++rr) {
      const int rb = (wid * 2 + rr) * 16;
#pragma unroll
      for (int ks = 0; ks < 4; ++ks) {
        const short8 pa = *(const short8*)&PTl[(rb + col) * 128 + ks * 32 + kgr * 8];
#pragma unroll
        for (int st = 0; st < 4; ++st) {
          const short8 vb = *(const short8*)&Vl[(st * 16 + col) * 128 + ks * 32 + kgr * 8];
          oacc[rr][st] = MFMA16(pa, vb, oacc[rr][st]);
        }
      }
    }
    __syncthreads();
  }
#pragma unroll
  for (int rr = 0; rr < 2; ++rr)
#pragma unroll
    for (int st = 0; st < 4; ++st)
#pragma unroll
      for (int r = 0; r < 4; ++r) {
        const int rpos = (wid * 2 + rr) * 16 + kgr * 4 + r;
        outc[(size_t)(b * 256 + rpos) * 1024 + h * 64 + st * 16 + col] =
            f2bf(oacc[rr][st][r]);
      }
}

// ---------------- host orchestration ----------------------------------------
extern "C" void kernel_launch(void* const* d_in, const int* in_sizes, int n_in,
                              void* d_out, int out_size, void* d_ws, size_t ws_size,
                              hipStream_t stream)
{
  const float* x     = (const float*)d_in[0];
  const float* pos   = (const float*)d_in[1];
  const float* bln1g = (const float*)d_in[2];
  const float* bln1b = (const float*)d_in[3];
  const float* bwq   = (const float*)d_in[4];
  const float* bwk   = (const float*)d_in[5];
  const float* bwv   = (const float*)d_in[6];
  const float* bwo   = (const float*)d_in[7];
  const float* bbo   = (const float*)d_in[8];
  const float* bln2g = (const float*)d_in[9];
  const float* bln2b = (const float*)d_in[10];
  const float* bw1   = (const float*)d_in[11];
  const float* bb1   = (const float*)d_in[12];
  const float* bw2   = (const float*)d_in[13];
  const float* bb2   = (const float*)d_in[14];
  const float* ln1g  = (const float*)d_in[15];
  const float* ln1b  = (const float*)d_in[16];
  const float* cwq   = (const float*)d_in[17];
  const float* cwk   = (const float*)d_in[18];
  const float* cwv   = (const float*)d_in[19];
  const float* cwo   = (const float*)d_in[20];
  const float* cbo   = (const float*)d_in[21];
  const float* cln2g = (const float*)d_in[22];
  const float* cln2b = (const float*)d_in[23];
  const float* fw1   = (const float*)d_in[24];
  const float* fb1   = (const float*)d_in[25];
  const float* fw2   = (const float*)d_in[26];
  const float* fb2   = (const float*)d_in[27];

  char* ws = (char*)d_ws;
  size_t off = 0;
  auto alloc = [&](size_t bytes) -> void* {
    void* p = ws + off; off += (bytes + 255) & ~(size_t)255; return p;
  };
  u16* wqkv_t = (u16*)alloc((size_t)3072 * 1024 * 2);
  u16* wo_t   = (u16*)alloc((size_t)1024 * 1024 * 2);
  u16* w1_t   = (u16*)alloc((size_t)4096 * 1024 * 2);
  u16* w2_t   = (u16*)alloc((size_t)1024 * 4096 * 2);
  u16* cwqv_t = (u16*)alloc((size_t)2048 * 1024 * 2);
  u16* cwk_t  = (u16*)alloc((size_t)1024 * 1024 * 2);
  u16* cwo_t  = (u16*)alloc((size_t)1024 * 1024 * 2);
  u16* fw1_t  = (u16*)alloc((size_t)4096 * 1024 * 2);
  u16* fw2_t  = (u16*)alloc((size_t)1024 * 4096 * 2);
  u16* pos_bf = (u16*)alloc((size_t)256 * 1024 * 2);
  u16* kkb    = (u16*)alloc((size_t)256 * 1024 * 2);
  u16* act_ln = (u16*)alloc((size_t)8192 * 1024 * 2);
  u16* qkv    = (u16*)alloc((size_t)8192 * 3072 * 2);
  u16* att    = (u16*)alloc((size_t)8192 * 1024 * 2);
  u16* ffb    = (u16*)alloc((size_t)8192 * 4096 * 2);
  float* yb   = (float*)alloc((size_t)8192 * 1024 * 4);
  if (ws_size < off) return;
  float* x2   = (float*)qkv;
  u16*   qv   = qkv;
  u16*   vt   = ffb;
  u16*   outc = att;
  float* zb   = yb;
  float* outp = (float*)d_out;

  const dim3 B256(256), B512(512);
  pack_head_w<<<dim3(2, 32, 16), B256, 0, stream>>>(bwq, wqkv_t);
  pack_head_w<<<dim3(2, 32, 16), B256, 0, stream>>>(bwk, wqkv_t + 1024 * 1024);
  pack_head_w<<<dim3(2, 32, 16), B256, 0, stream>>>(bwv, wqkv_t + 2048 * 1024);
  transpose_w<<<dim3(32, 32),  B256, 0, stream>>>(bwo, wo_t, 1024, 1024);
  transpose_w<<<dim3(128, 32), B256, 0, stream>>>(bw1, w1_t, 1024, 4096);
  transpose_w<<<dim3(32, 128), B256, 0, stream>>>(bw2, w2_t, 4096, 1024);
  pack_head_w<<<dim3(2, 32, 16), B256, 0, stream>>>(cwq, cwqv_t);
  pack_head_w<<<dim3(2, 32, 16), B256, 0, stream>>>(cwv, cwqv_t + 1024 * 1024);
  pack_head_w<<<dim3(2, 32, 16), B256, 0, stream>>>(cwk, cwk_t);
  transpose_w<<<dim3(32, 32),  B256, 0, stream>>>(cwo, cwo_t, 1024, 1024);
  transpose_w<<<dim3(128, 32), B256, 0, stream>>>(fw1, fw1_t, 1024, 4096);
  transpose_w<<<dim3(32, 128), B256, 0, stream>>>(fw2, fw2_t, 4096, 1024);
  cvt_bf16<<<dim3(256), B256, 0, stream>>>(pos, pos_bf);

  // ---- inner standard block ----
  ln_rows<<<dim3(8192), B256, 0, stream>>>(x, bln1g, bln1b, act_ln);
  gemm256<<<dim3(32, 12), B512, 0, stream>>>(act_ln, wqkv_t, nullptr, qkv,
      nullptr, nullptr, nullptr, 8192, 3072, 1024, 0);
  vtrans<<<dim3(16, 16, 8), B256, 0, stream>>>(qkv, vt, 2048, 3072);
  attn_inner<<<dim3(8, 16, 8), B512, 0, stream>>>(qkv, vt, att);
  gemm256<<<dim3(32, 4), B512, 0, stream>>>(att, wo_t, yb, nullptr,
      bbo, x, nullptr, 8192, 1024, 1024, 0);
  ln_rows<<<dim3(8192), B256, 0, stream>>>(yb, bln2g, bln2b, act_ln);
  gemm256<<<dim3(32, 16), B512, 0, stream>>>(act_ln, w1_t, nullptr, ffb,
      bb1, nullptr, nullptr, 8192, 4096, 1024, 1);
  gemm256<<<dim3(32, 4), B512, 0, stream>>>(ffb, w2_t, x2, nullptr,
      bb2, yb, x, 8192, 1024, 4096, 0);

  // ---- compressing cross-attention ----
  ln_rows<<<dim3(8192), B256, 0, stream>>>(x2, ln1g, ln1b, act_ln);
  gemm256<<<dim3(32, 8), B512, 0, stream>>>(act_ln, cwqv_t, nullptr, qv,
      nullptr, nullptr, nullptr, 8192, 2048, 1024, 0);
  gemm_bt<<<dim3(2, 8), B256, 0, stream>>>(pos_bf, cwk_t, nullptr, kkb,
      nullptr, nullptr, nullptr, 256, 1024, 1024, 0);
  vtrans<<<dim3(16, 16, 8), B256, 0, stream>>>(qv, vt, 1024, 2048);
  attn_cross<<<dim3(16, 8), B512, 0, stream>>>(qv, kkb, vt, outc);
  gemm_bt<<<dim3(16, 8), B256, 0, stream>>>(outc, cwo_t, zb, nullptr,
      cbo, nullptr, nullptr, 2048, 1024, 1024, 0);

  // ---- final FFN ----
  ln_rows<<<dim3(2048), B256, 0, stream>>>(zb, cln2g, cln2b, act_ln);
  gemm256<<<dim3(8, 16), B512, 0, stream>>>(act_ln, fw1_t, nullptr, ffb,
      fb1, nullptr, nullptr, 2048, 4096, 1024, 1);
  gemm_bt<<<dim3(16, 8), B256, 0, stream>>>(ffb, fw2_t, outp, nullptr,
      fb2, zb, nullptr, 2048, 1024, 4096, 0);
}

// Round 3
// 898.616 us; speedup vs baseline: 1.1329x; 1.1190x over previous
//
#include <hip/hip_runtime.h>
#include <stdint.h>

typedef unsigned short u16;
typedef __attribute__((ext_vector_type(8))) short short8;
typedef __attribute__((ext_vector_type(4))) float f32x4;

#define MFMA16(A,B,C) __builtin_amdgcn_mfma_f32_16x16x32_bf16(A,B,C,0,0,0)

static __device__ __forceinline__ u16 f2bf(float f) {
  union { float f; unsigned u; } v; v.f = f;
  unsigned r = v.u + 0x7FFFu + ((v.u >> 16) & 1u);
  return (u16)(r >> 16);
}

static __device__ __forceinline__ void gload16(const void* g, void* l) {
  __builtin_amdgcn_global_load_lds(
      (const __attribute__((address_space(1))) void*)(uintptr_t)g,
      (__attribute__((address_space(3))) void*)(uint32_t)(uintptr_t)l,
      16, 0, 0);
}

// bijective XCD swizzle (m204): consecutive new ids share bx (A-panel pinned
// per XCD, W streamed). Returns linear tile id w; bx = w/gy, by = w%gy.
static __device__ __forceinline__ int xcd_swz() {
  const int gx = gridDim.x, gy = gridDim.y, nwg = gx * gy;
  const int orig = blockIdx.y * gx + blockIdx.x;
  const int q = nwg >> 3, rm = nwg & 7, xcd = orig & 7, idx = orig >> 3;
  return (xcd < rm ? xcd * (q + 1) : rm * (q + 1) + (xcd - rm) * q) + idx;
}

// ============ 256x256 8-phase bf16 GEMM: C[M,N] = A[M,K] @ Wt[N,K]^T ========
#define PHASE(BUFO, MH, KH, STAGE_STMT, TAIL_STMT) do { \
  short8 af_[4], bf_[4]; \
  _Pragma("unroll") \
  for (int mf = 0; mf < 4; ++mf) { \
    const int r = wm0 + ((MH) * 4 + mf) * 16 + colL; \
    af_[mf] = *(const short8*)&lds[(BUFO) + ((KH) << 13) + r * 32 + ((kgr ^ ((r >> 1) & 3)) << 3)]; \
  } \
  _Pragma("unroll") \
  for (int nf = 0; nf < 4; ++nf) { \
    const int r = wn0 + nf * 16 + colL; \
    bf_[nf] = *(const short8*)&lds[(BUFO) + 16384 + ((KH) << 13) + r * 32 + ((kgr ^ ((r >> 1) & 3)) << 3)]; \
  } \
  STAGE_STMT; \
  __builtin_amdgcn_s_barrier(); \
  asm volatile("s_waitcnt lgkmcnt(0)" ::: "memory"); \
  __builtin_amdgcn_sched_barrier(0); \
  __builtin_amdgcn_s_setprio(1); \
  _Pragma("unroll") \
  for (int mf = 0; mf < 4; ++mf) \
    _Pragma("unroll") \
    for (int nf = 0; nf < 4; ++nf) \
      acc[(MH) * 4 + mf][nf] = MFMA16(af_[mf], bf_[nf], acc[(MH) * 4 + mf][nf]); \
  __builtin_amdgcn_s_setprio(0); \
  __builtin_amdgcn_sched_barrier(0); \
  TAIL_STMT; \
  __builtin_amdgcn_s_barrier(); \
} while (0)

__global__ __launch_bounds__(512, 1) void gemm256(
    const u16* __restrict__ A, const u16* __restrict__ Wt,
    float* __restrict__ Cf, u16* __restrict__ Cb,
    const float* __restrict__ bias,
    const float* __restrict__ res1, const float* __restrict__ res2,
    int M, int N, int K, int relu)
{
  __shared__ u16 lds[65536];  // 128 KiB
  const int tid = threadIdx.x;
  const int wid = tid >> 6, lane = tid & 63;
  const int colL = lane & 15, kgr = lane >> 4;
  const int wm0 = (wid & 1) * 128, wn0 = (wid >> 1) * 64;
  const int w = xcd_swz();
  const int m0 = (w / gridDim.y) * 256, n0 = (w % gridDim.y) * 256;
  const int NT = K >> 6;
  f32x4 acc[8][4] = {};

  auto stage = [&](const u16* src, int row0, int t_, int mat, int kh) {
    const size_t kb = (size_t)t_ * 64 + kh * 32;
    const int base = ((t_ & 1) << 15) + (mat << 14) + (kh << 13);
#pragma unroll
    for (int i = 0; i < 2; ++i) {
      const int c = i * 512 + tid;
      const int row = c >> 2, slot = c & 3;
      gload16(src + (size_t)(row0 + row) * K + kb + ((slot ^ ((row >> 1) & 3)) << 3),
              &lds[base + ((i * 512 + wid * 64) << 3)]);
    }
  };

  stage(A,  m0, 0, 0, 0); stage(Wt, n0, 0, 1, 0);
  stage(A,  m0, 0, 0, 1); stage(Wt, n0, 0, 1, 1);
  stage(A,  m0, 1, 0, 0); stage(Wt, n0, 1, 1, 0);
  asm volatile("s_waitcnt vmcnt(4)" ::: "memory");
  __builtin_amdgcn_s_barrier();

  for (int t = 0; t < NT; ++t) {
    const int bufo = (t & 1) << 15;
    PHASE(bufo, 0, 0, if (t + 1 < NT) stage(A,  m0, t + 1, 0, 1), );
    PHASE(bufo, 1, 0, if (t + 1 < NT) stage(Wt, n0, t + 1, 1, 1), );
    PHASE(bufo, 0, 1, if (t + 2 < NT) stage(A,  m0, t + 2, 0, 0), );
    PHASE(bufo, 1, 1, if (t + 2 < NT) stage(Wt, n0, t + 2, 1, 0),
          if (t < NT - 2) { asm volatile("s_waitcnt vmcnt(4)" ::: "memory"); }
          else            { asm volatile("s_waitcnt vmcnt(0)" ::: "memory"); } );
  }

#pragma unroll
  for (int mf = 0; mf < 8; ++mf) {
#pragma unroll
    for (int nf = 0; nf < 4; ++nf) {
      const int n = n0 + wn0 + nf * 16 + colL;
      const float bv = bias ? bias[n] : 0.f;
#pragma unroll
      for (int rr = 0; rr < 4; ++rr) {
        const int m = m0 + wm0 + mf * 16 + kgr * 4 + rr;
        const size_t off = (size_t)m * N + n;
        float v = acc[mf][nf][rr] + bv;
        if (res1) v += res1[off];
        if (res2) v += res2[off];
        if (relu) v = fmaxf(v, 0.f);
        if (Cf) Cf[off] = v; else Cb[off] = f2bf(v);
      }
    }
  }
}

// ============ 256x128 2-phase bf16 GEMM (for N=1024 shapes) =================
// 8 waves (4m x 2n), per-wave 64x64, BK=64. LDS 96KB:
// per buf 24576 elems: A[2kh][256][32] @0, B[2kh][128][32] @16384.
// Steady state: 6 loads in flight, vmcnt(6) per phase (counted, never drain).
#define PHASE2(BUFO, KH, STAGE_STMT, TAIL_STMT) do { \
  short8 af_[4], bf_[4]; \
  _Pragma("unroll") \
  for (int mf = 0; mf < 4; ++mf) { \
    const int r = wm0 + mf * 16 + colL; \
    af_[mf] = *(const short8*)&lds[(BUFO) + ((KH) << 13) + r * 32 + ((kgr ^ ((r >> 1) & 3)) << 3)]; \
  } \
  _Pragma("unroll") \
  for (int nf = 0; nf < 4; ++nf) { \
    const int r = wn0 + nf * 16 + colL; \
    bf_[nf] = *(const short8*)&lds[(BUFO) + 16384 + ((KH) << 12) + r * 32 + ((kgr ^ ((r >> 1) & 3)) << 3)]; \
  } \
  STAGE_STMT; \
  __builtin_amdgcn_s_barrier(); \
  asm volatile("s_waitcnt lgkmcnt(0)" ::: "memory"); \
  __builtin_amdgcn_sched_barrier(0); \
  __builtin_amdgcn_s_setprio(1); \
  _Pragma("unroll") \
  for (int mf = 0; mf < 4; ++mf) \
    _Pragma("unroll") \
    for (int nf = 0; nf < 4; ++nf) \
      acc[mf][nf] = MFMA16(af_[mf], bf_[nf], acc[mf][nf]); \
  __builtin_amdgcn_s_setprio(0); \
  __builtin_amdgcn_sched_barrier(0); \
  TAIL_STMT; \
  __builtin_amdgcn_s_barrier(); \
} while (0)

__global__ __launch_bounds__(512, 1) void gemm128n(
    const u16* __restrict__ A, const u16* __restrict__ Wt,
    float* __restrict__ Cf, u16* __restrict__ Cb,
    const float* __restrict__ bias,
    const float* __restrict__ res1, const float* __restrict__ res2,
    int M, int N, int K, int relu)
{
  __shared__ u16 lds[49152];  // 96 KiB
  const int tid = threadIdx.x;
  const int wid = tid >> 6, lane = tid & 63;
  const int colL = lane & 15, kgr = lane >> 4;
  const int wm0 = (wid >> 1) * 64, wn0 = (wid & 1) * 64;
  const int w = xcd_swz();
  const int m0 = (w / gridDim.y) * 256, n0 = (w % gridDim.y) * 128;
  const int NT = K >> 6;
  f32x4 acc[4][4] = {};

  auto stageA = [&](int t_, int kh) {
    const size_t kb = (size_t)t_ * 64 + kh * 32;
    const int base = (t_ & 1) * 24576 + (kh << 13);
#pragma unroll
    for (int i = 0; i < 2; ++i) {
      const int c = i * 512 + tid;
      const int row = c >> 2, slot = c & 3;
      gload16(A + (size_t)(m0 + row) * K + kb + ((slot ^ ((row >> 1) & 3)) << 3),
              &lds[base + ((i * 512 + wid * 64) << 3)]);
    }
  };
  auto stageB = [&](int t_, int kh) {
    const size_t kb = (size_t)t_ * 64 + kh * 32;
    const int base = (t_ & 1) * 24576 + 16384 + (kh << 12);
    const int row = tid >> 2, slot = tid & 3;
    gload16(Wt + (size_t)(n0 + row) * K + kb + ((slot ^ ((row >> 1) & 3)) << 3),
            &lds[base + ((wid * 64) << 3)]);
  };

  // prologue queue (oldest first): [t0kh0(3), t0kh1(3), t1kh0(3)]
  stageA(0, 0); stageB(0, 0);
  stageA(0, 1); stageB(0, 1);
  stageA(1, 0); stageB(1, 0);
  asm volatile("s_waitcnt vmcnt(6)" ::: "memory");  // t0kh0 done
  __builtin_amdgcn_s_barrier();

  for (int t = 0; t < NT; ++t) {
    const int bufo = (t & 1) * 24576;
    // phase0 reads kh0; stages (t+1)kh1 -> other buf (sealed since t-1 ph1)
    PHASE2(bufo, 0,
           if (t + 1 < NT) { stageA(t + 1, 1); stageB(t + 1, 1); },
           if (t + 1 < NT) { asm volatile("s_waitcnt vmcnt(6)" ::: "memory"); }
           else            { asm volatile("s_waitcnt vmcnt(0)" ::: "memory"); } );
    // phase1 reads kh1; stages (t+2)kh0 -> live buf kh0 (sealed after ph0)
    PHASE2(bufo, 1,
           if (t + 2 < NT) { stageA(t + 2, 0); stageB(t + 2, 0); },
           if (t < NT - 2)       { asm volatile("s_waitcnt vmcnt(6)" ::: "memory"); }
           else if (t == NT - 2) { asm volatile("s_waitcnt vmcnt(3)" ::: "memory"); }
           else                  { asm volatile("s_waitcnt vmcnt(0)" ::: "memory"); } );
  }

#pragma unroll
  for (int mf = 0; mf < 4; ++mf) {
#pragma unroll
    for (int nf = 0; nf < 4; ++nf) {
      const int n = n0 + wn0 + nf * 16 + colL;
      const float bv = bias ? bias[n] : 0.f;
#pragma unroll
      for (int rr = 0; rr < 4; ++rr) {
        const int m = m0 + wm0 + mf * 16 + kgr * 4 + rr;
        const size_t off = (size_t)m * N + n;
        float v = acc[mf][nf][rr] + bv;
        if (res1) v += res1[off];
        if (res2) v += res2[off];
        if (relu) v = fmaxf(v, 0.f);
        if (Cf) Cf[off] = v; else Cb[off] = f2bf(v);
      }
    }
  }
}

// ---------------- generic bf16 GEMM (128x128), for small shapes -------------
__global__ __launch_bounds__(256) void gemm_bt(
    const u16* __restrict__ A, const u16* __restrict__ Wt,
    float* __restrict__ Cf, u16* __restrict__ Cb,
    const float* __restrict__ bias,
    const float* __restrict__ res1, const float* __restrict__ res2,
    int M, int N, int K, int relu)
{
  __shared__ u16 lsA[128 * 32];
  __shared__ u16 lsB[128 * 32];
  const int tid = threadIdx.x;
  const int wid = tid >> 6, lane = tid & 63;
  const int col = lane & 15, kgr = lane >> 4;
  const int w = xcd_swz();
  const int m0 = (w / gridDim.y) * 128, n0 = (w % gridDim.y) * 128;
  const int wm = (wid >> 1) * 64, wn = (wid & 1) * 64;
  f32x4 acc[4][4] = {};
  const int nk = K >> 5;
  for (int kt = 0; kt < nk; ++kt) {
    const int k0 = kt << 5;
#pragma unroll
    for (int i = 0; i < 2; ++i) {
      int e = i * 2048 + tid * 8;
      gload16(A  + (size_t)(m0 + (e >> 5)) * K + k0 + (e & 31), &lsA[i * 2048 + wid * 512]);
      gload16(Wt + (size_t)(n0 + (e >> 5)) * K + k0 + (e & 31), &lsB[i * 2048 + wid * 512]);
    }
    __syncthreads();
    short8 af[4], bfr[4];
#pragma unroll
    for (int t = 0; t < 4; ++t) {
      af[t]  = *(const short8*)&lsA[(wm + t * 16 + col) * 32 + kgr * 8];
      bfr[t] = *(const short8*)&lsB[(wn + t * 16 + col) * 32 + kgr * 8];
    }
#pragma unroll
    for (int mt = 0; mt < 4; ++mt)
#pragma unroll
      for (int nt = 0; nt < 4; ++nt)
        acc[mt][nt] = MFMA16(af[mt], bfr[nt], acc[mt][nt]);
    __syncthreads();
  }
#pragma unroll
  for (int nt = 0; nt < 4; ++nt) {
    const int n = n0 + wn + nt * 16 + col;
    const float bv = bias ? bias[n] : 0.f;
#pragma unroll
    for (int mt = 0; mt < 4; ++mt) {
#pragma unroll
      for (int r = 0; r < 4; ++r) {
        const int m = m0 + wm + mt * 16 + kgr * 4 + r;
        const size_t off = (size_t)m * N + n;
        float v = acc[mt][nt][r] + bv;
        if (res1) v += res1[off];
        if (res2) v += res2[off];
        if (relu) v = fmaxf(v, 0.f);
        if (Cf) Cf[off] = v; else Cb[off] = f2bf(v);
      }
    }
  }
}

// ---------------- LayerNorm (fp32 in, bf16 out), one row (D=1024) per block --
__global__ __launch_bounds__(256) void ln_rows(
    const float* __restrict__ x, const float* __restrict__ g,
    const float* __restrict__ bt, u16* __restrict__ out)
{
  const int row = blockIdx.x, tid = threadIdx.x;
  const float4 v = ((const float4*)(x + (size_t)row * 1024))[tid];
  float s  = v.x + v.y + v.z + v.w;
  float ss = v.x * v.x + v.y * v.y + v.z * v.z + v.w * v.w;
#pragma unroll
  for (int off = 32; off; off >>= 1) {
    s  += __shfl_xor(s, off);
    ss += __shfl_xor(ss, off);
  }
  __shared__ float red[8];
  const int wid = tid >> 6, lane = tid & 63;
  if (lane == 0) { red[wid] = s; red[4 + wid] = ss; }
  __syncthreads();
  s  = red[0] + red[1] + red[2] + red[3];
  ss = red[4] + red[5] + red[6] + red[7];
  const float mean = s * 0.0009765625f;
  const float var  = ss * 0.0009765625f - mean * mean;
  const float rstd = rsqrtf(var + 1e-5f);
  const float4 gg = ((const float4*)g)[tid];
  const float4 bb = ((const float4*)bt)[tid];
  uint2 ov;
  ov.x = (unsigned)f2bf((v.x - mean) * rstd * gg.x + bb.x) |
         ((unsigned)f2bf((v.y - mean) * rstd * gg.y + bb.y) << 16);
  ov.y = (unsigned)f2bf((v.z - mean) * rstd * gg.z + bb.z) |
         ((unsigned)f2bf((v.w - mean) * rstd * gg.w + bb.w) << 16);
  *(uint2*)(out + (size_t)row * 1024 + tid * 4) = ov;
}

// ---------------- weight packing --------------------------------------------
__global__ __launch_bounds__(256) void transpose_w(
    const float* __restrict__ in, u16* __restrict__ out, int R, int C)
{
  __shared__ float t[32][33];
  const int c0 = blockIdx.x * 32, r0 = blockIdx.y * 32;
  const int tx = threadIdx.x & 31, ty = threadIdx.x >> 5;
#pragma unroll
  for (int i = 0; i < 32; i += 8)
    t[ty + i][tx] = in[(size_t)(r0 + ty + i) * C + c0 + tx];
  __syncthreads();
#pragma unroll
  for (int i = 0; i < 32; i += 8)
    out[(size_t)(c0 + ty + i) * R + r0 + tx] = f2bf(t[tx][ty + i]);
}

__global__ __launch_bounds__(256) void pack_head_w(
    const float* __restrict__ w, u16* __restrict__ out)
{
  __shared__ float t[32][33];
  const int h = blockIdx.z;
  const int s0 = blockIdx.x * 32, c0 = blockIdx.y * 32;
  const int tx = threadIdx.x & 31, ty = threadIdx.x >> 5;
#pragma unroll
  for (int i = 0; i < 32; i += 8)
    t[ty + i][tx] = w[((size_t)h * 1024 + c0 + ty + i) * 64 + s0 + tx];
  __syncthreads();
#pragma unroll
  for (int i = 0; i < 32; i += 8)
    out[((size_t)h * 64 + s0 + ty + i) * 1024 + c0 + tx] = f2bf(t[tx][ty + i]);
}

__global__ __launch_bounds__(256) void cvt_bf16(
    const float* __restrict__ in, u16* __restrict__ out)
{
  const int i = blockIdx.x * blockDim.x + threadIdx.x;
  const float4 v = ((const float4*)in)[i];
  uint2 ov;
  ov.x = (unsigned)f2bf(v.x) | ((unsigned)f2bf(v.y) << 16);
  ov.y = (unsigned)f2bf(v.z) | ((unsigned)f2bf(v.w) << 16);
  *(uint2*)(out + (size_t)i * 4) = ov;
}

__global__ __launch_bounds__(256) void vtrans(
    const u16* __restrict__ src, u16* __restrict__ dst, int coloff, int ld)
{
  __shared__ u16 tile[64][65];
  const int t0 = blockIdx.x * 64, h = blockIdx.y, b = blockIdx.z;
  const int lr = threadIdx.x >> 4;
  const int lc = (threadIdx.x & 15) * 4;
#pragma unroll
  for (int i = 0; i < 64; i += 16) {
    const u16* sp = src + (size_t)(b * 1024 + t0 + lr + i) * ld + coloff + h * 64 + lc;
    const uint2 v = *(const uint2*)sp;
    tile[lr + i][lc + 0] = (u16)(v.x & 0xffff);
    tile[lr + i][lc + 1] = (u16)(v.x >> 16);
    tile[lr + i][lc + 2] = (u16)(v.y & 0xffff);
    tile[lr + i][lc + 3] = (u16)(v.y >> 16);
  }
  __syncthreads();
#pragma unroll
  for (int i = 0; i < 64; i += 16) {
    const int s = lr + i;
    uint2 ov;
    ov.x = (unsigned)tile[lc + 0][s] | ((unsigned)tile[lc + 1][s] << 16);
    ov.y = (unsigned)tile[lc + 2][s] | ((unsigned)tile[lc + 3][s] << 16);
    *(uint2*)(dst + (size_t)((b * 16 + h) * 64 + s) * 1024 + t0 + lc) = ov;
  }
}

// ---------------- inner causal flash attention ------------------------------
__global__ __launch_bounds__(512) void attn_inner(
    const u16* __restrict__ qkv, const u16* __restrict__ vt,
    u16* __restrict__ att)
{
  __shared__ u16 Kl[128 * 64];
  __shared__ u16 Vl[64 * 128];
  __shared__ u16 Pl[8 * 16 * 128];
  const int tb = blockIdx.x, h = blockIdx.y, b = blockIdx.z;
  const int tid = threadIdx.x, wid = tid >> 6, lane = tid & 63;
  const int col = lane & 15, kgr = lane >> 4;
  const float scale = 0.03125f;
  short8 qf[2];
  {
    const int trow = tb * 128 + wid * 16 + col;
    const u16* qp = qkv + (size_t)(b * 1024 + trow) * 3072 + h * 64 + kgr * 8;
    qf[0] = *(const short8*)qp;
    qf[1] = *(const short8*)(qp + 32);
  }
  f32x4 o[4] = {};
  float mrun[4], lrun[4];
#pragma unroll
  for (int r = 0; r < 4; ++r) { mrun[r] = -1e30f; lrun[r] = 0.f; }

  for (int kt = 0; kt <= tb * 128; kt += 128) {
#pragma unroll
    for (int i = 0; i < 2; ++i) {
      int e = i * 4096 + tid * 8;
      gload16(qkv + (size_t)(b * 1024 + kt + (e >> 6)) * 3072 + 1024 + h * 64 + (e & 63),
              &Kl[i * 4096 + wid * 512]);
      gload16(vt + (size_t)((b * 16 + h) * 64 + (e >> 7)) * 1024 + kt + (e & 127),
              &Vl[i * 4096 + wid * 512]);
    }
    __syncthreads();
    f32x4 s[8];
#pragma unroll
    for (int nt = 0; nt < 8; ++nt) {
      const short8 k0 = *(const short8*)&Kl[(nt * 16 + col) * 64 + kgr * 8];
      const short8 k1 = *(const short8*)&Kl[(nt * 16 + col) * 64 + 32 + kgr * 8];
      f32x4 a = {};
      a = MFMA16(qf[0], k0, a);
      a = MFMA16(qf[1], k1, a);
      s[nt] = a;
    }
    float mx[4];
#pragma unroll
    for (int r = 0; r < 4; ++r) mx[r] = -1e30f;
    const int tbase = tb * 128 + wid * 16 + kgr * 4;
#pragma unroll
    for (int nt = 0; nt < 8; ++nt) {
      const int kp = kt + nt * 16 + col;
#pragma unroll
      for (int r = 0; r < 4; ++r) {
        float v = s[nt][r] * scale;
        if (kp > tbase + r) v = -1e30f;
        s[nt][r] = v;
        mx[r] = fmaxf(mx[r], v);
      }
    }
#pragma unroll
    for (int r = 0; r < 4; ++r)
#pragma unroll
      for (int off = 1; off < 16; off <<= 1)
        mx[r] = fmaxf(mx[r], __shfl_xor(mx[r], off));
    float f[4], rs[4];
#pragma unroll
    for (int r = 0; r < 4; ++r) {
      const float mn = fmaxf(mrun[r], mx[r]);
      f[r] = __expf(mrun[r] - mn);
      mrun[r] = mn;
      rs[r] = 0.f;
    }
#pragma unroll
    for (int nt = 0; nt < 8; ++nt)
#pragma unroll
      for (int r = 0; r < 4; ++r) {
        const float p = __expf(s[nt][r] - mrun[r]);
        s[nt][r] = p;
        rs[r] += p;
      }
#pragma unroll
    for (int r = 0; r < 4; ++r) {
#pragma unroll
      for (int off = 1; off < 16; off <<= 1)
        rs[r] += __shfl_xor(rs[r], off);
      lrun[r] = lrun[r] * f[r] + rs[r];
    }
#pragma unroll
    for (int st = 0; st < 4; ++st)
#pragma unroll
      for (int r = 0; r < 4; ++r)
        o[st][r] *= f[r];
    u16* pw = &Pl[wid * 2048];
#pragma unroll
    for (int nt = 0; nt < 8; ++nt)
#pragma unroll
      for (int r = 0; r < 4; ++r)
        pw[(kgr * 4 + r) * 128 + nt * 16 + col] = f2bf(s[nt][r]);
#pragma unroll
    for (int ks = 0; ks < 4; ++ks) {
      const short8 pa = *(const short8*)&pw[col * 128 + ks * 32 + kgr * 8];
#pragma unroll
      for (int st = 0; st < 4; ++st) {
        const short8 vb = *(const short8*)&Vl[(st * 16 + col) * 128 + ks * 32 + kgr * 8];
        o[st] = MFMA16(pa, vb, o[st]);
      }
    }
    __syncthreads();
  }
#pragma unroll
  for (int r = 0; r < 4; ++r) {
    const float inv = 1.f / lrun[r];
    const int t = tb * 128 + wid * 16 + kgr * 4 + r;
#pragma unroll
    for (int st = 0; st < 4; ++st)
      att[(size_t)(b * 1024 + t) * 1024 + h * 64 + st * 16 + col] =
          f2bf(o[st][r] * inv);
  }
}

// ---------------- compressing cross attention -------------------------------
__global__ __launch_bounds__(512) void attn_cross(
    const u16* __restrict__ qv, const u16* __restrict__ kk,
    const u16* __restrict__ vt, u16* __restrict__ outc)
{
  __shared__ u16 KKl[256 * 64];
  __shared__ u16 Vl[64 * 128];
  __shared__ u16 PTl[256 * 128];
  const int h = blockIdx.x, b = blockIdx.y;
  const int tid = threadIdx.x, wid = tid >> 6, lane = tid & 63;
  const int col = lane & 15, kgr = lane >> 4;
  const float scale = 0.03125f;
#pragma unroll
  for (int i = 0; i < 4; ++i) {
    int e = i * 4096 + tid * 8;
    gload16(kk + (size_t)(e >> 6) * 1024 + h * 64 + (e & 63), &KKl[i * 4096 + wid * 512]);
  }
  f32x4 oacc[2][4] = {};
  for (int tt = 0; tt < 8; ++tt) {
    const int t0 = tt * 128;
#pragma unroll
    for (int i = 0; i < 2; ++i) {
      int e = i * 4096 + tid * 8;
      gload16(vt + (size_t)((b * 16 + h) * 64 + (e >> 7)) * 1024 + t0 + (e & 127),
              &Vl[i * 4096 + wid * 512]);
    }
    short8 qf0, qf1;
    {
      const int trow = t0 + wid * 16 + col;
      const u16* qp = qv + (size_t)(b * 1024 + trow) * 2048 + h * 64 + kgr * 8;
      qf0 = *(const short8*)qp;
      qf1 = *(const short8*)(qp + 32);
    }
    __syncthreads();
    f32x4 s[16];
#pragma unroll
    for (int rt = 0; rt < 16; ++rt) {
      const short8 k0 = *(const short8*)&KKl[(rt * 16 + col) * 64 + kgr * 8];
      const short8 k1 = *(const short8*)&KKl[(rt * 16 + col) * 64 + 32 + kgr * 8];
      f32x4 a = {};
      a = MFMA16(qf0, k0, a);
      a = MFMA16(qf1, k1, a);
      s[rt] = a;
    }
    float mx[4];
#pragma unroll
    for (int r = 0; r < 4; ++r) mx[r] = -1e30f;
    const int tbase = t0 + wid * 16 + kgr * 4;
#pragma unroll
    for (int rt = 0; rt < 16; ++rt) {
      const int rp = rt * 16 + col;
#pragma unroll
      for (int r = 0; r < 4; ++r) {
        float v = s[rt][r] * scale;
        if (rp > tbase + r) v = -1e30f;
        s[rt][r] = v;
        mx[r] = fmaxf(mx[r], v);
      }
    }
#pragma unroll
    for (int r = 0; r < 4; ++r)
#pragma unroll
      for (int off = 1; off < 16; off <<= 1)
        mx[r] = fmaxf(mx[r], __shfl_xor(mx[r], off));
    float sm[4];
#pragma unroll
    for (int r = 0; r < 4; ++r) sm[r] = 0.f;
#pragma unroll
    for (int rt = 0; rt < 16; ++rt)
#pragma unroll
      for (int r = 0; r < 4; ++r) {
        const float p = __expf(s[rt][r] - mx[r]);
        s[rt][r] = p;
        sm[r] += p;
      }
#pragma unroll
    for (int r = 0; r < 4; ++r) {
#pragma unroll
      for (int off = 1; off < 16; off <<= 1)
        sm[r] += __shfl_xor(sm[r], off);
      sm[r] = 1.f / sm[r];
    }
#pragma unroll
    for (int rt = 0; rt < 16; ++rt)
#pragma unroll
      for (int r = 0; r < 4; ++r)
        PTl[(rt * 16 + col) * 128 + wid * 16 + kgr * 4 + r] = f2bf(s[rt][r] * sm[r]);
    __syncthreads();
#pragma unroll
    for (int rr = 0; rr < 2; ++rr) {
      const int rb = (wid * 2 + rr) * 16;
#pragma unroll
      for (int ks = 0; ks < 4; ++ks) {
        const short8 pa = *(const short8*)&PTl[(rb + col) * 128 + ks * 32 + kgr * 8];
#pragma unroll
        for (int st = 0; st < 4; ++st) {
          const short8 vb = *(const short8*)&Vl[(st * 16 + col) * 128 + ks * 32 + kgr * 8];
          oacc[rr][st] = MFMA16(pa, vb, oacc[rr][st]);
        }
      }
    }
    __syncthreads();
  }
#pragma unroll
  for (int rr = 0; rr < 2; ++rr)
#pragma unroll
    for (int st = 0; st < 4; ++st)
#pragma unroll
      for (int r = 0; r < 4; ++r) {
        const int rpos = (wid * 2 + rr) * 16 + kgr * 4 + r;
        outc[(size_t)(b * 256 + rpos) * 1024 + h * 64 + st * 16 + col] =
            f2bf(oacc[rr][st][r]);
      }
}

// ---------------- host orchestration ----------------------------------------
extern "C" void kernel_launch(void* const* d_in, const int* in_sizes, int n_in,
                              void* d_out, int out_size, void* d_ws, size_t ws_size,
                              hipStream_t stream)
{
  const float* x     = (const float*)d_in[0];
  const float* pos   = (const float*)d_in[1];
  const float* bln1g = (const float*)d_in[2];
  const float* bln1b = (const float*)d_in[3];
  const float* bwq   = (const float*)d_in[4];
  const float* bwk   = (const float*)d_in[5];
  const float* bwv   = (const float*)d_in[6];
  const float* bwo   = (const float*)d_in[7];
  const float* bbo   = (const float*)d_in[8];
  const float* bln2g = (const float*)d_in[9];
  const float* bln2b = (const float*)d_in[10];
  const float* bw1   = (const float*)d_in[11];
  const float* bb1   = (const float*)d_in[12];
  const float* bw2   = (const float*)d_in[13];
  const float* bb2   = (const float*)d_in[14];
  const float* ln1g  = (const float*)d_in[15];
  const float* ln1b  = (const float*)d_in[16];
  const float* cwq   = (const float*)d_in[17];
  const float* cwk   = (const float*)d_in[18];
  const float* cwv   = (const float*)d_in[19];
  const float* cwo   = (const float*)d_in[20];
  const float* cbo   = (const float*)d_in[21];
  const float* cln2g = (const float*)d_in[22];
  const float* cln2b = (const float*)d_in[23];
  const float* fw1   = (const float*)d_in[24];
  const float* fb1   = (const float*)d_in[25];
  const float* fw2   = (const float*)d_in[26];
  const float* fb2   = (const float*)d_in[27];

  char* ws = (char*)d_ws;
  size_t off = 0;
  auto alloc = [&](size_t bytes) -> void* {
    void* p = ws + off; off += (bytes + 255) & ~(size_t)255; return p;
  };
  u16* wqkv_t = (u16*)alloc((size_t)3072 * 1024 * 2);
  u16* wo_t   = (u16*)alloc((size_t)1024 * 1024 * 2);
  u16* w1_t   = (u16*)alloc((size_t)4096 * 1024 * 2);
  u16* w2_t   = (u16*)alloc((size_t)1024 * 4096 * 2);
  u16* cwqv_t = (u16*)alloc((size_t)2048 * 1024 * 2);
  u16* cwk_t  = (u16*)alloc((size_t)1024 * 1024 * 2);
  u16* cwo_t  = (u16*)alloc((size_t)1024 * 1024 * 2);
  u16* fw1_t  = (u16*)alloc((size_t)4096 * 1024 * 2);
  u16* fw2_t  = (u16*)alloc((size_t)1024 * 4096 * 2);
  u16* pos_bf = (u16*)alloc((size_t)256 * 1024 * 2);
  u16* kkb    = (u16*)alloc((size_t)256 * 1024 * 2);
  u16* act_ln = (u16*)alloc((size_t)8192 * 1024 * 2);
  u16* qkv    = (u16*)alloc((size_t)8192 * 3072 * 2);
  u16* att    = (u16*)alloc((size_t)8192 * 1024 * 2);
  u16* ffb    = (u16*)alloc((size_t)8192 * 4096 * 2);
  float* yb   = (float*)alloc((size_t)8192 * 1024 * 4);
  if (ws_size < off) return;
  float* x2   = (float*)qkv;
  u16*   qv   = qkv;
  u16*   vt   = ffb;
  u16*   outc = att;
  float* zb   = yb;
  float* outp = (float*)d_out;

  const dim3 B256(256), B512(512);
  pack_head_w<<<dim3(2, 32, 16), B256, 0, stream>>>(bwq, wqkv_t);
  pack_head_w<<<dim3(2, 32, 16), B256, 0, stream>>>(bwk, wqkv_t + 1024 * 1024);
  pack_head_w<<<dim3(2, 32, 16), B256, 0, stream>>>(bwv, wqkv_t + 2048 * 1024);
  transpose_w<<<dim3(32, 32),  B256, 0, stream>>>(bwo, wo_t, 1024, 1024);
  transpose_w<<<dim3(128, 32), B256, 0, stream>>>(bw1, w1_t, 1024, 4096);
  transpose_w<<<dim3(32, 128), B256, 0, stream>>>(bw2, w2_t, 4096, 1024);
  pack_head_w<<<dim3(2, 32, 16), B256, 0, stream>>>(cwq, cwqv_t);
  pack_head_w<<<dim3(2, 32, 16), B256, 0, stream>>>(cwv, cwqv_t + 1024 * 1024);
  pack_head_w<<<dim3(2, 32, 16), B256, 0, stream>>>(cwk, cwk_t);
  transpose_w<<<dim3(32, 32),  B256, 0, stream>>>(cwo, cwo_t, 1024, 1024);
  transpose_w<<<dim3(128, 32), B256, 0, stream>>>(fw1, fw1_t, 1024, 4096);
  transpose_w<<<dim3(32, 128), B256, 0, stream>>>(fw2, fw2_t, 4096, 1024);
  cvt_bf16<<<dim3(256), B256, 0, stream>>>(pos, pos_bf);

  // ---- inner standard block ----
  ln_rows<<<dim3(8192), B256, 0, stream>>>(x, bln1g, bln1b, act_ln);
  gemm256<<<dim3(32, 12), B512, 0, stream>>>(act_ln, wqkv_t, nullptr, qkv,
      nullptr, nullptr, nullptr, 8192, 3072, 1024, 0);
  vtrans<<<dim3(16, 16, 8), B256, 0, stream>>>(qkv, vt, 2048, 3072);
  attn_inner<<<dim3(8, 16, 8), B512, 0, stream>>>(qkv, vt, att);
  gemm128n<<<dim3(32, 8), B512, 0, stream>>>(att, wo_t, yb, nullptr,
      bbo, x, nullptr, 8192, 1024, 1024, 0);
  ln_rows<<<dim3(8192), B256, 0, stream>>>(yb, bln2g, bln2b, act_ln);
  gemm256<<<dim3(32, 16), B512, 0, stream>>>(act_ln, w1_t, nullptr, ffb,
      bb1, nullptr, nullptr, 8192, 4096, 1024, 1);
  gemm128n<<<dim3(32, 8), B512, 0, stream>>>(ffb, w2_t, x2, nullptr,
      bb2, yb, x, 8192, 1024, 4096, 0);

  // ---- compressing cross-attention ----
  ln_rows<<<dim3(8192), B256, 0, stream>>>(x2, ln1g, ln1b, act_ln);
  gemm256<<<dim3(32, 8), B512, 0, stream>>>(act_ln, cwqv_t, nullptr, qv,
      nullptr, nullptr, nullptr, 8192, 2048, 1024, 0);
  gemm_bt<<<dim3(2, 8), B256, 0, stream>>>(pos_bf, cwk_t, nullptr, kkb,
      nullptr, nullptr, nullptr, 256, 1024, 1024, 0);
  vtrans<<<dim3(16, 16, 8), B256, 0, stream>>>(qv, vt, 1024, 2048);
  attn_cross<<<dim3(16, 8), B512, 0, stream>>>(qv, kkb, vt, outc);
  gemm_bt<<<dim3(16, 8), B256, 0, stream>>>(outc, cwo_t, zb, nullptr,
      cbo, nullptr, nullptr, 2048, 1024, 1024, 0);

  // ---- final FFN ----
  ln_rows<<<dim3(2048), B256, 0, stream>>>(zb, cln2g, cln2b, act_ln);
  gemm256<<<dim3(8, 16), B512, 0, stream>>>(act_ln, fw1_t, nullptr, ffb,
      fb1, nullptr, nullptr, 2048, 4096, 1024, 1);
  gemm_bt<<<dim3(16, 8), B256, 0, stream>>>(ffb, fw2_t, outp, nullptr,
      fb2, zb, nullptr, 2048, 1024, 4096, 0);
}

// Round 4
// 783.288 us; speedup vs baseline: 1.2997x; 1.1472x over previous
//
#include <hip/hip_runtime.h>
#include <stdint.h>

typedef unsigned short u16;
typedef __attribute__((ext_vector_type(8))) short short8;
typedef __attribute__((ext_vector_type(4))) float f32x4;

#define MFMA16(A,B,C) __builtin_amdgcn_mfma_f32_16x16x32_bf16(A,B,C,0,0,0)

static __device__ __forceinline__ u16 f2bf(float f) {
  union { float f; unsigned u; } v; v.f = f;
  unsigned r = v.u + 0x7FFFu + ((v.u >> 16) & 1u);
  return (u16)(r >> 16);
}

static __device__ __forceinline__ void gload16(const void* g, void* l) {
  __builtin_amdgcn_global_load_lds(
      (const __attribute__((address_space(1))) void*)(uintptr_t)g,
      (__attribute__((address_space(3))) void*)(uint32_t)(uintptr_t)l,
      16, 0, 0);
}

// bijective XCD swizzle (m204)
static __device__ __forceinline__ int xcd_swz() {
  const int gx = gridDim.x, gy = gridDim.y, nwg = gx * gy;
  const int orig = blockIdx.y * gx + blockIdx.x;
  const int q = nwg >> 3, rm = nwg & 7, xcd = orig & 7, idx = orig >> 3;
  return (xcd < rm ? xcd * (q + 1) : rm * (q + 1) + (xcd - rm) * q) + idx;
}

// ============ 256x256 8-phase bf16 GEMM: C[M,N] = A[M,K] @ Wt[N,K]^T ========
#define PHASE(BUFO, MH, KH, STAGE_STMT, TAIL_STMT) do { \
  short8 af_[4], bf_[4]; \
  _Pragma("unroll") \
  for (int mf = 0; mf < 4; ++mf) { \
    const int r = wm0 + ((MH) * 4 + mf) * 16 + colL; \
    af_[mf] = *(const short8*)&lds[(BUFO) + ((KH) << 13) + r * 32 + ((kgr ^ ((r >> 1) & 3)) << 3)]; \
  } \
  _Pragma("unroll") \
  for (int nf = 0; nf < 4; ++nf) { \
    const int r = wn0 + nf * 16 + colL; \
    bf_[nf] = *(const short8*)&lds[(BUFO) + 16384 + ((KH) << 13) + r * 32 + ((kgr ^ ((r >> 1) & 3)) << 3)]; \
  } \
  STAGE_STMT; \
  __builtin_amdgcn_s_barrier(); \
  asm volatile("s_waitcnt lgkmcnt(0)" ::: "memory"); \
  __builtin_amdgcn_sched_barrier(0); \
  __builtin_amdgcn_s_setprio(1); \
  _Pragma("unroll") \
  for (int mf = 0; mf < 4; ++mf) \
    _Pragma("unroll") \
    for (int nf = 0; nf < 4; ++nf) \
      acc[(MH) * 4 + mf][nf] = MFMA16(af_[mf], bf_[nf], acc[(MH) * 4 + mf][nf]); \
  __builtin_amdgcn_s_setprio(0); \
  __builtin_amdgcn_sched_barrier(0); \
  TAIL_STMT; \
  __builtin_amdgcn_s_barrier(); \
} while (0)

__global__ __launch_bounds__(512, 1) void gemm256(
    const u16* __restrict__ A, const u16* __restrict__ Wt,
    float* __restrict__ Cf, u16* __restrict__ Cb,
    const float* __restrict__ bias,
    const float* __restrict__ res1, const float* __restrict__ res2,
    int M, int N, int K, int relu)
{
  __shared__ u16 lds[65536];  // 128 KiB
  const int tid = threadIdx.x;
  const int wid = tid >> 6, lane = tid & 63;
  const int colL = lane & 15, kgr = lane >> 4;
  const int wm0 = (wid & 1) * 128, wn0 = (wid >> 1) * 64;
  const int w = xcd_swz();
  const int m0 = (w / gridDim.y) * 256, n0 = (w % gridDim.y) * 256;
  const int NT = K >> 6;
  f32x4 acc[8][4] = {};

  auto stage = [&](const u16* src, int row0, int t_, int mat, int kh) {
    const size_t kb = (size_t)t_ * 64 + kh * 32;
    const int base = ((t_ & 1) << 15) + (mat << 14) + (kh << 13);
#pragma unroll
    for (int i = 0; i < 2; ++i) {
      const int c = i * 512 + tid;
      const int row = c >> 2, slot = c & 3;
      gload16(src + (size_t)(row0 + row) * K + kb + ((slot ^ ((row >> 1) & 3)) << 3),
              &lds[base + ((i * 512 + wid * 64) << 3)]);
    }
  };

  stage(A,  m0, 0, 0, 0); stage(Wt, n0, 0, 1, 0);
  stage(A,  m0, 0, 0, 1); stage(Wt, n0, 0, 1, 1);
  stage(A,  m0, 1, 0, 0); stage(Wt, n0, 1, 1, 0);
  asm volatile("s_waitcnt vmcnt(4)" ::: "memory");
  __builtin_amdgcn_s_barrier();

  for (int t = 0; t < NT; ++t) {
    const int bufo = (t & 1) << 15;
    PHASE(bufo, 0, 0, if (t + 1 < NT) stage(A,  m0, t + 1, 0, 1), );
    PHASE(bufo, 1, 0, if (t + 1 < NT) stage(Wt, n0, t + 1, 1, 1), );
    PHASE(bufo, 0, 1, if (t + 2 < NT) stage(A,  m0, t + 2, 0, 0), );
    PHASE(bufo, 1, 1, if (t + 2 < NT) stage(Wt, n0, t + 2, 1, 0),
          if (t < NT - 2) { asm volatile("s_waitcnt vmcnt(4)" ::: "memory"); }
          else            { asm volatile("s_waitcnt vmcnt(0)" ::: "memory"); } );
  }

#pragma unroll
  for (int mf = 0; mf < 8; ++mf) {
#pragma unroll
    for (int nf = 0; nf < 4; ++nf) {
      const int n = n0 + wn0 + nf * 16 + colL;
      const float bv = bias ? bias[n] : 0.f;
#pragma unroll
      for (int rr = 0; rr < 4; ++rr) {
        const int m = m0 + wm0 + mf * 16 + kgr * 4 + rr;
        const size_t off = (size_t)m * N + n;
        float v = acc[mf][nf][rr] + bv;
        if (res1) v += res1[off];
        if (res2) v += res2[off];
        if (relu) v = fmaxf(v, 0.f);
        if (Cf) Cf[off] = v; else Cb[off] = f2bf(v);
      }
    }
  }
}

// ============ 256x128 2-phase bf16 GEMM (for N-narrow shapes) ===============
#define PHASE2(BUFO, KH, STAGE_STMT, TAIL_STMT) do { \
  short8 af_[4], bf_[4]; \
  _Pragma("unroll") \
  for (int mf = 0; mf < 4; ++mf) { \
    const int r = wm0 + mf * 16 + colL; \
    af_[mf] = *(const short8*)&lds[(BUFO) + ((KH) << 13) + r * 32 + ((kgr ^ ((r >> 1) & 3)) << 3)]; \
  } \
  _Pragma("unroll") \
  for (int nf = 0; nf < 4; ++nf) { \
    const int r = wn0 + nf * 16 + colL; \
    bf_[nf] = *(const short8*)&lds[(BUFO) + 16384 + ((KH) << 12) + r * 32 + ((kgr ^ ((r >> 1) & 3)) << 3)]; \
  } \
  STAGE_STMT; \
  __builtin_amdgcn_s_barrier(); \
  asm volatile("s_waitcnt lgkmcnt(0)" ::: "memory"); \
  __builtin_amdgcn_sched_barrier(0); \
  __builtin_amdgcn_s_setprio(1); \
  _Pragma("unroll") \
  for (int mf = 0; mf < 4; ++mf) \
    _Pragma("unroll") \
    for (int nf = 0; nf < 4; ++nf) \
      acc[mf][nf] = MFMA16(af_[mf], bf_[nf], acc[mf][nf]); \
  __builtin_amdgcn_s_setprio(0); \
  __builtin_amdgcn_sched_barrier(0); \
  TAIL_STMT; \
  __builtin_amdgcn_s_barrier(); \
} while (0)

__global__ __launch_bounds__(512, 1) void gemm128n(
    const u16* __restrict__ A, const u16* __restrict__ Wt,
    float* __restrict__ Cf, u16* __restrict__ Cb,
    const float* __restrict__ bias,
    const float* __restrict__ res1, const float* __restrict__ res2,
    int M, int N, int K, int relu)
{
  __shared__ u16 lds[49152];  // 96 KiB
  const int tid = threadIdx.x;
  const int wid = tid >> 6, lane = tid & 63;
  const int colL = lane & 15, kgr = lane >> 4;
  const int wm0 = (wid >> 1) * 64, wn0 = (wid & 1) * 64;
  const int w = xcd_swz();
  const int m0 = (w / gridDim.y) * 256, n0 = (w % gridDim.y) * 128;
  const int NT = K >> 6;
  f32x4 acc[4][4] = {};

  auto stageA = [&](int t_, int kh) {
    const size_t kb = (size_t)t_ * 64 + kh * 32;
    const int base = (t_ & 1) * 24576 + (kh << 13);
#pragma unroll
    for (int i = 0; i < 2; ++i) {
      const int c = i * 512 + tid;
      const int row = c >> 2, slot = c & 3;
      gload16(A + (size_t)(m0 + row) * K + kb + ((slot ^ ((row >> 1) & 3)) << 3),
              &lds[base + ((i * 512 + wid * 64) << 3)]);
    }
  };
  auto stageB = [&](int t_, int kh) {
    const size_t kb = (size_t)t_ * 64 + kh * 32;
    const int base = (t_ & 1) * 24576 + 16384 + (kh << 12);
    const int row = tid >> 2, slot = tid & 3;
    gload16(Wt + (size_t)(n0 + row) * K + kb + ((slot ^ ((row >> 1) & 3)) << 3),
            &lds[base + ((wid * 64) << 3)]);
  };

  stageA(0, 0); stageB(0, 0);
  stageA(0, 1); stageB(0, 1);
  stageA(1, 0); stageB(1, 0);
  asm volatile("s_waitcnt vmcnt(6)" ::: "memory");
  __builtin_amdgcn_s_barrier();

  for (int t = 0; t < NT; ++t) {
    const int bufo = (t & 1) * 24576;
    PHASE2(bufo, 0,
           if (t + 1 < NT) { stageA(t + 1, 1); stageB(t + 1, 1); },
           if (t + 1 < NT) { asm volatile("s_waitcnt vmcnt(6)" ::: "memory"); }
           else            { asm volatile("s_waitcnt vmcnt(0)" ::: "memory"); } );
    PHASE2(bufo, 1,
           if (t + 2 < NT) { stageA(t + 2, 0); stageB(t + 2, 0); },
           if (t < NT - 2)       { asm volatile("s_waitcnt vmcnt(6)" ::: "memory"); }
           else if (t == NT - 2) { asm volatile("s_waitcnt vmcnt(3)" ::: "memory"); }
           else                  { asm volatile("s_waitcnt vmcnt(0)" ::: "memory"); } );
  }

#pragma unroll
  for (int mf = 0; mf < 4; ++mf) {
#pragma unroll
    for (int nf = 0; nf < 4; ++nf) {
      const int n = n0 + wn0 + nf * 16 + colL;
      const float bv = bias ? bias[n] : 0.f;
#pragma unroll
      for (int rr = 0; rr < 4; ++rr) {
        const int m = m0 + wm0 + mf * 16 + kgr * 4 + rr;
        const size_t off = (size_t)m * N + n;
        float v = acc[mf][nf][rr] + bv;
        if (res1) v += res1[off];
        if (res2) v += res2[off];
        if (relu) v = fmaxf(v, 0.f);
        if (Cf) Cf[off] = v; else Cb[off] = f2bf(v);
      }
    }
  }
}

// ---------------- generic bf16 GEMM (128x128), for small shapes -------------
__global__ __launch_bounds__(256) void gemm_bt(
    const u16* __restrict__ A, const u16* __restrict__ Wt,
    float* __restrict__ Cf, u16* __restrict__ Cb,
    const float* __restrict__ bias,
    const float* __restrict__ res1, const float* __restrict__ res2,
    int M, int N, int K, int relu)
{
  __shared__ u16 lsA[128 * 32];
  __shared__ u16 lsB[128 * 32];
  const int tid = threadIdx.x;
  const int wid = tid >> 6, lane = tid & 63;
  const int col = lane & 15, kgr = lane >> 4;
  const int w = xcd_swz();
  const int m0 = (w / gridDim.y) * 128, n0 = (w % gridDim.y) * 128;
  const int wm = (wid >> 1) * 64, wn = (wid & 1) * 64;
  f32x4 acc[4][4] = {};
  const int nk = K >> 5;
  for (int kt = 0; kt < nk; ++kt) {
    const int k0 = kt << 5;
#pragma unroll
    for (int i = 0; i < 2; ++i) {
      const int e = i * 2048 + tid * 8;
      const int row = e >> 5, slot = (e >> 3) & 3;
      const int cs = k0 + ((slot ^ ((row >> 1) & 3)) << 3);
      gload16(A  + (size_t)(m0 + row) * K + cs, &lsA[i * 2048 + wid * 512]);
      gload16(Wt + (size_t)(n0 + row) * K + cs, &lsB[i * 2048 + wid * 512]);
    }
    __syncthreads();
    short8 af[4], bfr[4];
#pragma unroll
    for (int t = 0; t < 4; ++t) {
      const int ra = wm + t * 16 + col, rb = wn + t * 16 + col;
      af[t]  = *(const short8*)&lsA[ra * 32 + ((kgr ^ ((ra >> 1) & 3)) << 3)];
      bfr[t] = *(const short8*)&lsB[rb * 32 + ((kgr ^ ((rb >> 1) & 3)) << 3)];
    }
#pragma unroll
    for (int mt = 0; mt < 4; ++mt)
#pragma unroll
      for (int nt = 0; nt < 4; ++nt)
        acc[mt][nt] = MFMA16(af[mt], bfr[nt], acc[mt][nt]);
    __syncthreads();
  }
#pragma unroll
  for (int nt = 0; nt < 4; ++nt) {
    const int n = n0 + wn + nt * 16 + col;
    const float bv = bias ? bias[n] : 0.f;
#pragma unroll
    for (int mt = 0; mt < 4; ++mt) {
#pragma unroll
      for (int r = 0; r < 4; ++r) {
        const int m = m0 + wm + mt * 16 + kgr * 4 + r;
        const size_t off = (size_t)m * N + n;
        float v = acc[mt][nt][r] + bv;
        if (res1) v += res1[off];
        if (res2) v += res2[off];
        if (relu) v = fmaxf(v, 0.f);
        if (Cf) Cf[off] = v; else Cb[off] = f2bf(v);
      }
    }
  }
}

// ---------------- LayerNorm (fp32 in, bf16 out) -----------------------------
__global__ __launch_bounds__(256) void ln_rows(
    const float* __restrict__ x, const float* __restrict__ g,
    const float* __restrict__ bt, u16* __restrict__ out)
{
  const int row = blockIdx.x, tid = threadIdx.x;
  const float4 v = ((const float4*)(x + (size_t)row * 1024))[tid];
  float s  = v.x + v.y + v.z + v.w;
  float ss = v.x * v.x + v.y * v.y + v.z * v.z + v.w * v.w;
#pragma unroll
  for (int off = 32; off; off >>= 1) {
    s  += __shfl_xor(s, off);
    ss += __shfl_xor(ss, off);
  }
  __shared__ float red[8];
  const int wid = tid >> 6, lane = tid & 63;
  if (lane == 0) { red[wid] = s; red[4 + wid] = ss; }
  __syncthreads();
  s  = red[0] + red[1] + red[2] + red[3];
  ss = red[4] + red[5] + red[6] + red[7];
  const float mean = s * 0.0009765625f;
  const float var  = ss * 0.0009765625f - mean * mean;
  const float rstd = rsqrtf(var + 1e-5f);
  const float4 gg = ((const float4*)g)[tid];
  const float4 bb = ((const float4*)bt)[tid];
  uint2 ov;
  ov.x = (unsigned)f2bf((v.x - mean) * rstd * gg.x + bb.x) |
         ((unsigned)f2bf((v.y - mean) * rstd * gg.y + bb.y) << 16);
  ov.y = (unsigned)f2bf((v.z - mean) * rstd * gg.z + bb.z) |
         ((unsigned)f2bf((v.w - mean) * rstd * gg.w + bb.w) << 16);
  *(uint2*)(out + (size_t)row * 1024 + tid * 4) = ov;
}

// ---------------- weight packing --------------------------------------------
__global__ __launch_bounds__(256) void transpose_w(
    const float* __restrict__ in, u16* __restrict__ out, int R, int C)
{
  __shared__ float t[32][33];
  const int c0 = blockIdx.x * 32, r0 = blockIdx.y * 32;
  const int tx = threadIdx.x & 31, ty = threadIdx.x >> 5;
#pragma unroll
  for (int i = 0; i < 32; i += 8)
    t[ty + i][tx] = in[(size_t)(r0 + ty + i) * C + c0 + tx];
  __syncthreads();
#pragma unroll
  for (int i = 0; i < 32; i += 8)
    out[(size_t)(c0 + ty + i) * R + r0 + tx] = f2bf(t[tx][ty + i]);
}

__global__ __launch_bounds__(256) void pack_head_w(
    const float* __restrict__ w, u16* __restrict__ out)
{
  __shared__ float t[32][33];
  const int h = blockIdx.z;
  const int s0 = blockIdx.x * 32, c0 = blockIdx.y * 32;
  const int tx = threadIdx.x & 31, ty = threadIdx.x >> 5;
#pragma unroll
  for (int i = 0; i < 32; i += 8)
    t[ty + i][tx] = w[((size_t)h * 1024 + c0 + ty + i) * 64 + s0 + tx];
  __syncthreads();
#pragma unroll
  for (int i = 0; i < 32; i += 8)
    out[((size_t)h * 64 + s0 + ty + i) * 1024 + c0 + tx] = f2bf(t[tx][ty + i]);
}

__global__ __launch_bounds__(256) void cvt_bf16(
    const float* __restrict__ in, u16* __restrict__ out)
{
  const int i = blockIdx.x * blockDim.x + threadIdx.x;
  const float4 v = ((const float4*)in)[i];
  uint2 ov;
  ov.x = (unsigned)f2bf(v.x) | ((unsigned)f2bf(v.y) << 16);
  ov.y = (unsigned)f2bf(v.z) | ((unsigned)f2bf(v.w) << 16);
  *(uint2*)(out + (size_t)i * 4) = ov;
}

__global__ __launch_bounds__(256) void vtrans(
    const u16* __restrict__ src, u16* __restrict__ dst, int coloff, int ld)
{
  __shared__ u16 tile[64][65];
  const int t0 = blockIdx.x * 64, h = blockIdx.y, b = blockIdx.z;
  const int lr = threadIdx.x >> 4;
  const int lc = (threadIdx.x & 15) * 4;
#pragma unroll
  for (int i = 0; i < 64; i += 16) {
    const u16* sp = src + (size_t)(b * 1024 + t0 + lr + i) * ld + coloff + h * 64 + lc;
    const uint2 v = *(const uint2*)sp;
    tile[lr + i][lc + 0] = (u16)(v.x & 0xffff);
    tile[lr + i][lc + 1] = (u16)(v.x >> 16);
    tile[lr + i][lc + 2] = (u16)(v.y & 0xffff);
    tile[lr + i][lc + 3] = (u16)(v.y >> 16);
  }
  __syncthreads();
#pragma unroll
  for (int i = 0; i < 64; i += 16) {
    const int s = lr + i;
    uint2 ov;
    ov.x = (unsigned)tile[lc + 0][s] | ((unsigned)tile[lc + 1][s] << 16);
    ov.y = (unsigned)tile[lc + 2][s] | ((unsigned)tile[lc + 3][s] << 16);
    *(uint2*)(dst + (size_t)((b * 16 + h) * 64 + s) * 1024 + t0 + lc) = ov;
  }
}

// ---------------- inner causal flash attention ------------------------------
// All LDS tiles XOR-swizzled (16B-unit ^ (row&7)); K,V via pre-swizzled
// global source (rule #21); only the diagonal K-tile applies the causal mask.
__global__ __launch_bounds__(512) void attn_inner(
    const u16* __restrict__ qkv, const u16* __restrict__ vt,
    u16* __restrict__ att)
{
  __shared__ u16 Kl[128 * 64];
  __shared__ u16 Vl[64 * 128];
  __shared__ u16 Pl[8 * 16 * 128];
  const int tb = blockIdx.x, h = blockIdx.y, b = blockIdx.z;
  const int tid = threadIdx.x, wid = tid >> 6, lane = tid & 63;
  const int col = lane & 15, kgr = lane >> 4;
  const float scale = 0.03125f;
  short8 qf[2];
  {
    const int trow = tb * 128 + wid * 16 + col;
    const u16* qp = qkv + (size_t)(b * 1024 + trow) * 3072 + h * 64 + kgr * 8;
    qf[0] = *(const short8*)qp;
    qf[1] = *(const short8*)(qp + 32);
  }
  f32x4 o[4] = {};
  float mrun[4], lrun[4];
#pragma unroll
  for (int r = 0; r < 4; ++r) { mrun[r] = -1e30f; lrun[r] = 0.f; }

  for (int kt = 0; kt <= tb * 128; kt += 128) {
#pragma unroll
    for (int i = 0; i < 2; ++i) {
      const int e = i * 4096 + tid * 8;
      const int rk = e >> 6, uk = (e >> 3) & 7;
      gload16(qkv + (size_t)(b * 1024 + kt + rk) * 3072 + 1024 + h * 64 +
                  ((uk ^ (rk & 7)) << 3),
              &Kl[i * 4096 + wid * 512]);
      const int rv = e >> 7, uv = (e >> 3) & 15;
      gload16(vt + (size_t)((b * 16 + h) * 64 + rv) * 1024 + kt +
                  ((uv ^ (rv & 7)) << 3),
              &Vl[i * 4096 + wid * 512]);
    }
    __syncthreads();
    f32x4 s[8];
#pragma unroll
    for (int nt = 0; nt < 8; ++nt) {
      const int rk = nt * 16 + col;
      const short8 k0 = *(const short8*)&Kl[rk * 64 + ((kgr ^ (rk & 7)) << 3)];
      const short8 k1 = *(const short8*)&Kl[rk * 64 + (((kgr + 4) ^ (rk & 7)) << 3)];
      f32x4 a = {};
      a = MFMA16(qf[0], k0, a);
      a = MFMA16(qf[1], k1, a);
      s[nt] = a;
    }
    float mx[4];
#pragma unroll
    for (int r = 0; r < 4; ++r) mx[r] = -1e30f;
    const int tbase = tb * 128 + wid * 16 + kgr * 4;
    if (kt == tb * 128) {  // diagonal tile: apply causal mask
#pragma unroll
      for (int nt = 0; nt < 8; ++nt) {
        const int kp = kt + nt * 16 + col;
#pragma unroll
        for (int r = 0; r < 4; ++r) {
          float v = s[nt][r] * scale;
          if (kp > tbase + r) v = -1e30f;
          s[nt][r] = v;
          mx[r] = fmaxf(mx[r], v);
        }
      }
    } else {
#pragma unroll
      for (int nt = 0; nt < 8; ++nt)
#pragma unroll
        for (int r = 0; r < 4; ++r) {
          const float v = s[nt][r] * scale;
          s[nt][r] = v;
          mx[r] = fmaxf(mx[r], v);
        }
    }
#pragma unroll
    for (int r = 0; r < 4; ++r)
#pragma unroll
      for (int off = 1; off < 16; off <<= 1)
        mx[r] = fmaxf(mx[r], __shfl_xor(mx[r], off));
    float f[4], rs[4];
#pragma unroll
    for (int r = 0; r < 4; ++r) {
      const float mn = fmaxf(mrun[r], mx[r]);
      f[r] = __expf(mrun[r] - mn);
      mrun[r] = mn;
      rs[r] = 0.f;
    }
#pragma unroll
    for (int nt = 0; nt < 8; ++nt)
#pragma unroll
      for (int r = 0; r < 4; ++r) {
        const float p = __expf(s[nt][r] - mrun[r]);
        s[nt][r] = p;
        rs[r] += p;
      }
#pragma unroll
    for (int r = 0; r < 4; ++r) {
#pragma unroll
      for (int off = 1; off < 16; off <<= 1)
        rs[r] += __shfl_xor(rs[r], off);
      lrun[r] = lrun[r] * f[r] + rs[r];
    }
#pragma unroll
    for (int st = 0; st < 4; ++st)
#pragma unroll
      for (int r = 0; r < 4; ++r)
        o[st][r] *= f[r];
    u16* pw = &Pl[wid * 2048];
#pragma unroll
    for (int nt = 0; nt < 8; ++nt)
#pragma unroll
      for (int r = 0; r < 4; ++r) {
        const int rp = kgr * 4 + r;
        pw[rp * 128 + ((nt * 16 + col) ^ ((rp & 7) << 3))] = f2bf(s[nt][r]);
      }
#pragma unroll
    for (int ks = 0; ks < 4; ++ks) {
      const short8 pa = *(const short8*)&pw[col * 128 +
          ((ks * 32 + kgr * 8) ^ ((col & 7) << 3))];
#pragma unroll
      for (int st = 0; st < 4; ++st) {
        const int rv = st * 16 + col;
        const short8 vb = *(const short8*)&Vl[rv * 128 +
            (((ks * 4 + kgr) ^ (rv & 7)) << 3)];
        o[st] = MFMA16(pa, vb, o[st]);
      }
    }
    __syncthreads();
  }
#pragma unroll
  for (int r = 0; r < 4; ++r) {
    const float inv = 1.f / lrun[r];
    const int t = tb * 128 + wid * 16 + kgr * 4 + r;
#pragma unroll
    for (int st = 0; st < 4; ++st)
      att[(size_t)(b * 1024 + t) * 1024 + h * 64 + st * 16 + col] =
          f2bf(o[st][r] * inv);
  }
}

// ---------------- compressing cross attention -------------------------------
__global__ __launch_bounds__(512) void attn_cross(
    const u16* __restrict__ qv, const u16* __restrict__ kk,
    const u16* __restrict__ vt, u16* __restrict__ outc)
{
  __shared__ u16 KKl[256 * 64];
  __shared__ u16 Vl[64 * 128];
  __shared__ u16 PTl[256 * 128];
  const int h = blockIdx.x, b = blockIdx.y;
  const int tid = threadIdx.x, wid = tid >> 6, lane = tid & 63;
  const int col = lane & 15, kgr = lane >> 4;
  const float scale = 0.03125f;
#pragma unroll
  for (int i = 0; i < 4; ++i) {
    const int e = i * 4096 + tid * 8;
    const int rk = e >> 6, uk = (e >> 3) & 7;
    gload16(kk + (size_t)rk * 1024 + h * 64 + ((uk ^ (rk & 7)) << 3),
            &KKl[i * 4096 + wid * 512]);
  }
  f32x4 oacc[2][4] = {};
  for (int tt = 0; tt < 8; ++tt) {
    const int t0 = tt * 128;
#pragma unroll
    for (int i = 0; i < 2; ++i) {
      const int e = i * 4096 + tid * 8;
      const int rv = e >> 7, uv = (e >> 3) & 15;
      gload16(vt + (size_t)((b * 16 + h) * 64 + rv) * 1024 + t0 +
                  ((uv ^ (rv & 7)) << 3),
              &Vl[i * 4096 + wid * 512]);
    }
    short8 qf0, qf1;
    {
      const int trow = t0 + wid * 16 + col;
      const u16* qp = qv + (size_t)(b * 1024 + trow) * 2048 + h * 64 + kgr * 8;
      qf0 = *(const short8*)qp;
      qf1 = *(const short8*)(qp + 32);
    }
    __syncthreads();
    f32x4 s[16];
#pragma unroll
    for (int rt = 0; rt < 16; ++rt) {
      const int rk = rt * 16 + col;
      const short8 k0 = *(const short8*)&KKl[rk * 64 + ((kgr ^ (rk & 7)) << 3)];
      const short8 k1 = *(const short8*)&KKl[rk * 64 + (((kgr + 4) ^ (rk & 7)) << 3)];
      f32x4 a = {};
      a = MFMA16(qf0, k0, a);
      a = MFMA16(qf1, k1, a);
      s[rt] = a;
    }
    float mx[4];
#pragma unroll
    for (int r = 0; r < 4; ++r) mx[r] = -1e30f;
    const int tbase = t0 + wid * 16 + kgr * 4;
    if (t0 < 256) {  // only first two T-tiles have masked elements
#pragma unroll
      for (int rt = 0; rt < 16; ++rt) {
        const int rp = rt * 16 + col;
#pragma unroll
        for (int r = 0; r < 4; ++r) {
          float v = s[rt][r] * scale;
          if (rp > tbase + r) v = -1e30f;
          s[rt][r] = v;
          mx[r] = fmaxf(mx[r], v);
        }
      }
    } else {
#pragma unroll
      for (int rt = 0; rt < 16; ++rt)
#pragma unroll
        for (int r = 0; r < 4; ++r) {
          const float v = s[rt][r] * scale;
          s[rt][r] = v;
          mx[r] = fmaxf(mx[r], v);
        }
    }
#pragma unroll
    for (int r = 0; r < 4; ++r)
#pragma unroll
      for (int off = 1; off < 16; off <<= 1)
        mx[r] = fmaxf(mx[r], __shfl_xor(mx[r], off));
    float sm[4];
#pragma unroll
    for (int r = 0; r < 4; ++r) sm[r] = 0.f;
#pragma unroll
    for (int rt = 0; rt < 16; ++rt)
#pragma unroll
      for (int r = 0; r < 4; ++r) {
        const float p = __expf(s[rt][r] - mx[r]);
        s[rt][r] = p;
        sm[r] += p;
      }
#pragma unroll
    for (int r = 0; r < 4; ++r) {
#pragma unroll
      for (int off = 1; off < 16; off <<= 1)
        sm[r] += __shfl_xor(sm[r], off);
      sm[r] = 1.f / sm[r];
    }
#pragma unroll
    for (int rt = 0; rt < 16; ++rt)
#pragma unroll
      for (int r = 0; r < 4; ++r) {
        const int rpt = rt * 16 + col;
        PTl[rpt * 128 + ((wid * 16 + kgr * 4 + r) ^ ((rpt & 7) << 3))] =
            f2bf(s[rt][r] * sm[r]);
      }
    __syncthreads();
#pragma unroll
    for (int rr = 0; rr < 2; ++rr) {
      const int rb = (wid * 2 + rr) * 16;
#pragma unroll
      for (int ks = 0; ks < 4; ++ks) {
        const int rpt = rb + col;
        const short8 pa = *(const short8*)&PTl[rpt * 128 +
            ((ks * 32 + kgr * 8) ^ ((rpt & 7) << 3))];
#pragma unroll
        for (int st = 0; st < 4; ++st) {
          const int rv = st * 16 + col;
          const short8 vb = *(const short8*)&Vl[rv * 128 +
              (((ks * 4 + kgr) ^ (rv & 7)) << 3)];
          oacc[rr][st] = MFMA16(pa, vb, oacc[rr][st]);
        }
      }
    }
    __syncthreads();
  }
#pragma unroll
  for (int rr = 0; rr < 2; ++rr)
#pragma unroll
    for (int st = 0; st < 4; ++st)
#pragma unroll
      for (int r = 0; r < 4; ++r) {
        const int rpos = (wid * 2 + rr) * 16 + kgr * 4 + r;
        outc[(size_t)(b * 256 + rpos) * 1024 + h * 64 + st * 16 + col] =
            f2bf(oacc[rr][st][r]);
      }
}

// ---------------- host orchestration ----------------------------------------
extern "C" void kernel_launch(void* const* d_in, const int* in_sizes, int n_in,
                              void* d_out, int out_size, void* d_ws, size_t ws_size,
                              hipStream_t stream)
{
  const float* x     = (const float*)d_in[0];
  const float* pos   = (const float*)d_in[1];
  const float* bln1g = (const float*)d_in[2];
  const float* bln1b = (const float*)d_in[3];
  const float* bwq   = (const float*)d_in[4];
  const float* bwk   = (const float*)d_in[5];
  const float* bwv   = (const float*)d_in[6];
  const float* bwo   = (const float*)d_in[7];
  const float* bbo   = (const float*)d_in[8];
  const float* bln2g = (const float*)d_in[9];
  const float* bln2b = (const float*)d_in[10];
  const float* bw1   = (const float*)d_in[11];
  const float* bb1   = (const float*)d_in[12];
  const float* bw2   = (const float*)d_in[13];
  const float* bb2   = (const float*)d_in[14];
  const float* ln1g  = (const float*)d_in[15];
  const float* ln1b  = (const float*)d_in[16];
  const float* cwq   = (const float*)d_in[17];
  const float* cwk   = (const float*)d_in[18];
  const float* cwv   = (const float*)d_in[19];
  const float* cwo   = (const float*)d_in[20];
  const float* cbo   = (const float*)d_in[21];
  const float* cln2g = (const float*)d_in[22];
  const float* cln2b = (const float*)d_in[23];
  const float* fw1   = (const float*)d_in[24];
  const float* fb1   = (const float*)d_in[25];
  const float* fw2   = (const float*)d_in[26];
  const float* fb2   = (const float*)d_in[27];

  char* ws = (char*)d_ws;
  size_t off = 0;
  auto alloc = [&](size_t bytes) -> void* {
    void* p = ws + off; off += (bytes + 255) & ~(size_t)255; return p;
  };
  u16* wqkv_t = (u16*)alloc((size_t)3072 * 1024 * 2);
  u16* wo_t   = (u16*)alloc((size_t)1024 * 1024 * 2);
  u16* w1_t   = (u16*)alloc((size_t)4096 * 1024 * 2);
  u16* w2_t   = (u16*)alloc((size_t)1024 * 4096 * 2);
  u16* cwqv_t = (u16*)alloc((size_t)2048 * 1024 * 2);
  u16* cwk_t  = (u16*)alloc((size_t)1024 * 1024 * 2);
  u16* cwo_t  = (u16*)alloc((size_t)1024 * 1024 * 2);
  u16* fw1_t  = (u16*)alloc((size_t)4096 * 1024 * 2);
  u16* fw2_t  = (u16*)alloc((size_t)1024 * 4096 * 2);
  u16* pos_bf = (u16*)alloc((size_t)256 * 1024 * 2);
  u16* kkb    = (u16*)alloc((size_t)256 * 1024 * 2);
  u16* act_ln = (u16*)alloc((size_t)8192 * 1024 * 2);
  u16* qkv    = (u16*)alloc((size_t)8192 * 3072 * 2);
  u16* att    = (u16*)alloc((size_t)8192 * 1024 * 2);
  u16* ffb    = (u16*)alloc((size_t)8192 * 4096 * 2);
  float* yb   = (float*)alloc((size_t)8192 * 1024 * 4);
  if (ws_size < off) return;
  float* x2   = (float*)qkv;
  u16*   qv   = qkv;
  u16*   vt   = ffb;
  u16*   outc = att;
  float* zb   = yb;
  float* outp = (float*)d_out;

  const dim3 B256(256), B512(512);
  pack_head_w<<<dim3(2, 32, 16), B256, 0, stream>>>(bwq, wqkv_t);
  pack_head_w<<<dim3(2, 32, 16), B256, 0, stream>>>(bwk, wqkv_t + 1024 * 1024);
  pack_head_w<<<dim3(2, 32, 16), B256, 0, stream>>>(bwv, wqkv_t + 2048 * 1024);
  transpose_w<<<dim3(32, 32),  B256, 0, stream>>>(bwo, wo_t, 1024, 1024);
  transpose_w<<<dim3(128, 32), B256, 0, stream>>>(bw1, w1_t, 1024, 4096);
  transpose_w<<<dim3(32, 128), B256, 0, stream>>>(bw2, w2_t, 4096, 1024);
  pack_head_w<<<dim3(2, 32, 16), B256, 0, stream>>>(cwq, cwqv_t);
  pack_head_w<<<dim3(2, 32, 16), B256, 0, stream>>>(cwv, cwqv_t + 1024 * 1024);
  pack_head_w<<<dim3(2, 32, 16), B256, 0, stream>>>(cwk, cwk_t);
  transpose_w<<<dim3(32, 32),  B256, 0, stream>>>(cwo, cwo_t, 1024, 1024);
  transpose_w<<<dim3(128, 32), B256, 0, stream>>>(fw1, fw1_t, 1024, 4096);
  transpose_w<<<dim3(32, 128), B256, 0, stream>>>(fw2, fw2_t, 4096, 1024);
  cvt_bf16<<<dim3(256), B256, 0, stream>>>(pos, pos_bf);

  // ---- inner standard block ----
  ln_rows<<<dim3(8192), B256, 0, stream>>>(x, bln1g, bln1b, act_ln);
  gemm256<<<dim3(32, 12), B512, 0, stream>>>(act_ln, wqkv_t, nullptr, qkv,
      nullptr, nullptr, nullptr, 8192, 3072, 1024, 0);
  vtrans<<<dim3(16, 16, 8), B256, 0, stream>>>(qkv, vt, 2048, 3072);
  attn_inner<<<dim3(8, 16, 8), B512, 0, stream>>>(qkv, vt, att);
  gemm128n<<<dim3(32, 8), B512, 0, stream>>>(att, wo_t, yb, nullptr,
      bbo, x, nullptr, 8192, 1024, 1024, 0);
  ln_rows<<<dim3(8192), B256, 0, stream>>>(yb, bln2g, bln2b, act_ln);
  gemm256<<<dim3(32, 16), B512, 0, stream>>>(act_ln, w1_t, nullptr, ffb,
      bb1, nullptr, nullptr, 8192, 4096, 1024, 1);
  gemm128n<<<dim3(32, 8), B512, 0, stream>>>(ffb, w2_t, x2, nullptr,
      bb2, yb, x, 8192, 1024, 4096, 0);

  // ---- compressing cross-attention ----
  ln_rows<<<dim3(8192), B256, 0, stream>>>(x2, ln1g, ln1b, act_ln);
  gemm256<<<dim3(32, 8), B512, 0, stream>>>(act_ln, cwqv_t, nullptr, qv,
      nullptr, nullptr, nullptr, 8192, 2048, 1024, 0);
  gemm_bt<<<dim3(2, 8), B256, 0, stream>>>(pos_bf, cwk_t, nullptr, kkb,
      nullptr, nullptr, nullptr, 256, 1024, 1024, 0);
  vtrans<<<dim3(16, 16, 8), B256, 0, stream>>>(qv, vt, 1024, 2048);
  attn_cross<<<dim3(16, 8), B512, 0, stream>>>(qv, kkb, vt, outc);
  gemm_bt<<<dim3(16, 8), B256, 0, stream>>>(outc, cwo_t, zb, nullptr,
      cbo, nullptr, nullptr, 2048, 1024, 1024, 0);

  // ---- final FFN ----
  ln_rows<<<dim3(2048), B256, 0, stream>>>(zb, cln2g, cln2b, act_ln);
  gemm128n<<<dim3(8, 32), B512, 0, stream>>>(act_ln, fw1_t, nullptr, ffb,
      fb1, nullptr, nullptr, 2048, 4096, 1024, 1);
  gemm_bt<<<dim3(16, 8), B256, 0, stream>>>(ffb, fw2_t, outp, nullptr,
      fb2, zb, nullptr, 2048, 1024, 4096, 0);
}